// Round 7
// baseline (294.835 us; speedup 1.0000x reference)
//
#include <hip/hip_runtime.h>
#include <cstdint>
#include <cstddef>

// Problem constants
#define BB   2
#define SS   2048
#define DD   512
#define HH   8
#define HDIM 64

typedef __attribute__((ext_vector_type(8)))  short          s16x8;
typedef __attribute__((ext_vector_type(8)))  unsigned short u16x8;
typedef __attribute__((ext_vector_type(16))) float          f32x16;

static __device__ __forceinline__ unsigned short f2bf(float f) {
  union { float f; unsigned u; } x; x.f = f;
  unsigned r = x.u + 0x7fffu + ((x.u >> 16) & 1u);  // RNE
  return (unsigned short)(r >> 16);
}
// truncating bf16 pack: result = bf(hi)<<16 | bf(lo), ONE v_perm_b32
static __device__ __forceinline__ unsigned packtrunc(float lo, float hi) {
  return __builtin_amdgcn_perm(__float_as_uint(hi), __float_as_uint(lo), 0x07060302u);
}

// sigmoid scale folded into Q: -1/sqrt(64) * log2(e)
#define QSCALE (-0.18033688011111543f)

// ---------------- fused cvt + QKV projection ---------------------------------------
// grid (M/64=64, N/64=8, 3) = 1536 blocks = 6/CU. 256 threads = 4 waves in 2x2,
// each wave 32x32 out via one 32x32x16 MFMA chain. Reg-prefetch + LDS dbuf.
// Outputs (all bf16):
//   z=0 Q: head-split [B][H][S][HD], pre-scaled by QSCALE
//   z=1 K: MFMA A-frag order:  [bh][kt=s/32][c=d/16][ lane=(d8&1)*32+(s&31) ][ j=d&7 ]
//   z=2 V: MFMA B-frag order:  [bh][kt=s/32][dh=d/32][cc=(s/16)&1][ lane=((s/8)&1)*32+(d&31) ][ j=s&7 ]
// so attn loads every fragment as ONE contiguous 1KB dwordx4 stream.
__global__ __launch_bounds__(256) void proj_kernel(
    const float* __restrict__ x,
    const float* __restrict__ wq, const float* __restrict__ wk, const float* __restrict__ wv,
    const float* __restrict__ bq, const float* __restrict__ bk, const float* __restrict__ bv,
    unsigned short* __restrict__ qo, unsigned short* __restrict__ ko,
    unsigned short* __restrict__ vt) {
  __shared__ unsigned short As[2][64 * 40];  // 64 x 32 bf16, pad->40
  __shared__ unsigned short Bs[2][64 * 40];

  const int z = blockIdx.z;
  const float* w; const float* bias;
  if (z == 0)      { w = wq; bias = bq; }
  else if (z == 1) { w = wk; bias = bk; }
  else             { w = wv; bias = bv; }

  const int t = threadIdx.x;
  const int lane = t & 63, wave = t >> 6;
  const int ln = lane & 31, hi = lane >> 5;
  const int wr = wave >> 1, wc = wave & 1;
  const int m0 = blockIdx.x * 64, n0 = blockIdx.y * 64;

  // staging: 512 float4 chunks per matrix, 2 per thread
  float4 ar[2], br[2];
#pragma unroll
  for (int i = 0; i < 2; i++) {
    int c = t + i * 256;
    ar[i] = *(const float4*)&x[(size_t)(m0 + (c >> 3)) * DD + (c & 7) * 4];
    br[i] = *(const float4*)&w[(size_t)(n0 + (c >> 3)) * DD + (c & 7) * 4];
  }
#pragma unroll
  for (int i = 0; i < 2; i++) {
    int c = t + i * 256;
    uint2 ua, ub;
    ua.x = packtrunc(ar[i].x, ar[i].y); ua.y = packtrunc(ar[i].z, ar[i].w);
    ub.x = packtrunc(br[i].x, br[i].y); ub.y = packtrunc(br[i].z, br[i].w);
    *(uint2*)&As[0][(c >> 3) * 40 + (c & 7) * 4] = ua;
    *(uint2*)&Bs[0][(c >> 3) * 40 + (c & 7) * 4] = ub;
  }
  __syncthreads();

  f32x16 acc = {};

#pragma unroll 2
  for (int kt = 0; kt < 16; kt++) {
    const int cur = kt & 1, nxt = cur ^ 1;
    if (kt < 15) {
      int k0 = (kt + 1) * 32;
#pragma unroll
      for (int i = 0; i < 2; i++) {
        int c = t + i * 256;
        ar[i] = *(const float4*)&x[(size_t)(m0 + (c >> 3)) * DD + k0 + (c & 7) * 4];
        br[i] = *(const float4*)&w[(size_t)(n0 + (c >> 3)) * DD + k0 + (c & 7) * 4];
      }
    }
#pragma unroll
    for (int c = 0; c < 2; c++) {
      s16x8 af = *(const s16x8*)&As[cur][(wr * 32 + ln) * 40 + c * 16 + hi * 8];
      s16x8 bf = *(const s16x8*)&Bs[cur][(wc * 32 + ln) * 40 + c * 16 + hi * 8];
      acc = __builtin_amdgcn_mfma_f32_32x32x16_bf16(af, bf, acc, 0, 0, 0);
    }
    if (kt < 15) {
#pragma unroll
      for (int i = 0; i < 2; i++) {
        int c = t + i * 256;
        uint2 ua, ub;
        ua.x = packtrunc(ar[i].x, ar[i].y); ua.y = packtrunc(ar[i].z, ar[i].w);
        ub.x = packtrunc(br[i].x, br[i].y); ub.y = packtrunc(br[i].z, br[i].w);
        *(uint2*)&As[nxt][(c >> 3) * 40 + (c & 7) * 4] = ua;
        *(uint2*)&Bs[nxt][(c >> 3) * 40 + (c & 7) * 4] = ub;
      }
    }
    __syncthreads();
  }

  // Epilogue. C layout: col(n) = ln, row(m) local = (r&3) + 8*(r>>2) + 4*hi.
  const int h = blockIdx.y;
  const int bidx = m0 >> 11;
  const int sbase = (m0 & 2047) + wr * 32;   // multiple of 32
  const int hd = wc * 32 + ln;
  const float bval = bias[n0 + hd];
  const size_t bhb = (size_t)(bidx * HH + h) * SS * HDIM;

  if (z == 0) {  // Q: [bh][s][hd], scaled
#pragma unroll
    for (int r = 0; r < 16; r++) {
      int s = sbase + (r & 3) + 8 * (r >> 2) + 4 * hi;
      qo[bhb + (size_t)s * HDIM + hd] = f2bf((acc[r] + bval) * QSCALE);
    }
  } else if (z == 1) {  // K fragment order
    const int c = hd >> 4, hk = (hd >> 3) & 1, j = hd & 7;
    const int kts = sbase >> 5;
    unsigned short* kd = ko + bhb + ((size_t)kts * 4 + c) * 512 + j;
#pragma unroll
    for (int r = 0; r < 16; r++) {
      int off = (r & 3) + 8 * (r >> 2) + 4 * hi;  // s & 31
      kd[(hk * 32 + off) * 8] = f2bf(acc[r] + bval);
    }
  } else {  // V fragment order; s,s+1 adjacent in j -> dword stores
    const int kts = sbase >> 5;
    unsigned short* vd = vt + bhb + ((size_t)kts * 4 + wc * 2) * 512 + ln * 8 + 4 * hi;
#pragma unroll
    for (int g = 0; g < 4; g++) {
      unsigned short* vg = vd + ((g >> 1) * 512) + (g & 1) * 256;
#pragma unroll
      for (int j = 0; j < 4; j += 2) {
        unsigned pk = (unsigned)f2bf(acc[g * 4 + j] + bval) |
                      ((unsigned)f2bf(acc[g * 4 + j + 1] + bval) << 16);
        *(unsigned*)&vg[j] = pk;
      }
    }
  }
}

// ---------------- fused sigmoid attention: 8 waves/block, frag-direct loads ---------
// grid (32, 16) = 512 blocks of 512 threads = 8 waves; block = 64 queries; each wave
// owns a key EIGHTH (8 tiles of 32, strided 8). 2 blocks/CU x 8 waves = 16 waves/CU
// = 4 waves/SIMD (R6 was 2 — grid-capped). K/V fragments are contiguous 1KB dwordx4
// loads (frag-ordered by proj), register double-buffered. Zero barriers in the loop.
// 64 KB staged 8->4->sum O-reduction at the end.
__global__ __launch_bounds__(512, 4) void attn_kernel(
    const unsigned short* __restrict__ qb,
    const unsigned short* __restrict__ kfb,
    const unsigned short* __restrict__ vfb,
    float* __restrict__ out) {
  __shared__ __align__(16) float red[4 * 4096];  // 64 KB

  const int t = threadIdx.x;
  const int lane = t & 63, wave = t >> 6;   // wave in 0..7
  const int ln = lane & 31, hi = lane >> 5;
  // XCD swizzle: blocks of one bh all land on XCD bh%8 (16 ≡ 0 mod 8)
  const int fid = blockIdx.y * 32 + blockIdx.x;
  const int bh = fid & 15, qx = fid >> 4;
  const int b = bh >> 3, h = bh & 7;
  const unsigned short* qp = qb + (size_t)bh * SS * HDIM;
  const unsigned short* kfp = kfb + (size_t)bh * SS * HDIM;
  const unsigned short* vfp = vfb + (size_t)bh * SS * HDIM;
  const int q0 = qx * 64;

  // Q fragments (B-operand: n=q on lane, k=d), whole kernel in regs
  s16x8 qf[2][4];
#pragma unroll
  for (int qs = 0; qs < 2; qs++)
#pragma unroll
    for (int c = 0; c < 4; c++)
      qf[qs][c] = *(const s16x8*)&qp[(size_t)(q0 + qs * 32 + ln) * HDIM + c * 16 + hi * 8];

  f32x16 o00 = {}, o01 = {}, o10 = {}, o11 = {};

  // frag-ordered: chunk(kt_glob, sub) at (kt_glob*4+sub)*512 + lane*8; this wave's
  // tile i has kt_glob = i*8 + wave -> base advances 16384 per i.
  s16x8 kf[2][4], vf[2][4];
  int foff = wave * 4 * 512 + lane * 8;
#pragma unroll
  for (int c = 0; c < 4; c++) {
    kf[0][c] = *(const s16x8*)&kfp[foff + c * 512];
    vf[0][c] = *(const s16x8*)&vfp[foff + c * 512];
  }
  foff += 16384;

#pragma unroll 2
  for (int i = 0; i < 8; i++) {
    const int cur = i & 1, nxt = cur ^ 1;
    if (i < 7) {  // prefetch next tile's fragments (contiguous streams)
#pragma unroll
      for (int c = 0; c < 4; c++) {
        kf[nxt][c] = *(const s16x8*)&kfp[foff + c * 512];
        vf[nxt][c] = *(const s16x8*)&vfp[foff + c * 512];
      }
      foff += 16384;
    }

    // QK^T: S^T[key_local on (r,hi)][q on ln], two q-subtiles
    f32x16 st0 = {}, st1 = {};
#pragma unroll
    for (int c = 0; c < 4; c++) {
      st0 = __builtin_amdgcn_mfma_f32_32x32x16_bf16(kf[cur][c], qf[0][c], st0, 0, 0, 0);
      st1 = __builtin_amdgcn_mfma_f32_32x32x16_bf16(kf[cur][c], qf[1][c], st1, 0, 0, 0);
    }

    // sigmoid = rcp(1 + exp2(st)) (scale folded into Q), truncating bf16 pack
    unsigned pgx[2][4], pgy[2][4];
#pragma unroll
    for (int qs = 0; qs < 2; qs++) {
      f32x16 stq = qs ? st1 : st0;
#pragma unroll
      for (int g = 0; g < 4; g++) {
        float p0 = __builtin_amdgcn_rcpf(1.0f + __builtin_amdgcn_exp2f(stq[4 * g + 0]));
        float p1 = __builtin_amdgcn_rcpf(1.0f + __builtin_amdgcn_exp2f(stq[4 * g + 1]));
        float p2 = __builtin_amdgcn_rcpf(1.0f + __builtin_amdgcn_exp2f(stq[4 * g + 2]));
        float p3 = __builtin_amdgcn_rcpf(1.0f + __builtin_amdgcn_exp2f(stq[4 * g + 3]));
        pgx[qs][g] = packtrunc(p0, p1);
        pgy[qs][g] = packtrunc(p2, p3);
      }
    }

    // PV: A-operand P built via lane^32 exchange (validated pattern)
#pragma unroll
    for (int c = 0; c < 2; c++) {
      const int gk = 2 * c + hi, gs = 2 * c + (hi ^ 1);
#pragma unroll
      for (int qs = 0; qs < 2; qs++) {
        unsigned rx = __shfl_xor((int)pgx[qs][gs], 32, 64);
        unsigned ry = __shfl_xor((int)pgy[qs][gs], 32, 64);
        union { unsigned u[4]; s16x8 v; } pu;
        pu.u[0] = hi ? rx : pgx[qs][gk];
        pu.u[1] = hi ? ry : pgy[qs][gk];
        pu.u[2] = hi ? pgx[qs][gk] : rx;
        pu.u[3] = hi ? pgy[qs][gk] : ry;
        if (qs == 0) {
          o00 = __builtin_amdgcn_mfma_f32_32x32x16_bf16(pu.v, vf[cur][c], o00, 0, 0, 0);
          o01 = __builtin_amdgcn_mfma_f32_32x32x16_bf16(pu.v, vf[cur][2 + c], o01, 0, 0, 0);
        } else {
          o10 = __builtin_amdgcn_mfma_f32_32x32x16_bf16(pu.v, vf[cur][c], o10, 0, 0, 0);
          o11 = __builtin_amdgcn_mfma_f32_32x32x16_bf16(pu.v, vf[cur][2 + c], o11, 0, 0, 0);
        }
      }
    }
  }

  // staged 8->4->sum cross-wave O reduction in 64 KB
  if (wave >= 4) {  // waves 4..7 deposit partials in slots 0..3
#pragma unroll
    for (int qs = 0; qs < 2; qs++)
#pragma unroll
      for (int dh = 0; dh < 2; dh++) {
        f32x16 ov = qs ? (dh ? o11 : o10) : (dh ? o01 : o00);
#pragma unroll
        for (int r = 0; r < 16; r++) {
          int ql = qs * 32 + (r & 3) + 8 * (r >> 2) + 4 * hi;
          red[(wave - 4) * 4096 + ql * 64 + dh * 32 + ln] = ov[r];
        }
      }
  }
  __syncthreads();
  if (wave < 4) {  // waves 0..3 accumulate into their slot
#pragma unroll
    for (int qs = 0; qs < 2; qs++)
#pragma unroll
      for (int dh = 0; dh < 2; dh++) {
        f32x16 ov = qs ? (dh ? o11 : o10) : (dh ? o01 : o00);
#pragma unroll
        for (int r = 0; r < 16; r++) {
          int ql = qs * 32 + (r & 3) + 8 * (r >> 2) + 4 * hi;
          int idx = wave * 4096 + ql * 64 + dh * 32 + ln;
          red[idx] += ov[r];
        }
      }
  }
  __syncthreads();
  const float4* r0 = (const float4*)red;
  const float4* r1 = (const float4*)(red + 4096);
  const float4* r2 = (const float4*)(red + 8192);
  const float4* r3 = (const float4*)(red + 12288);
#pragma unroll
  for (int j = 0; j < 2; j++) {
    int g = t + j * 512;   // 1024 float4s total
    float4 s0 = r0[g], s1 = r1[g], s2 = r2[g], s3 = r3[g];
    float4 s;
    s.x = (s0.x + s1.x) + (s2.x + s3.x);
    s.y = (s0.y + s1.y) + (s2.y + s3.y);
    s.z = (s0.z + s1.z) + (s2.z + s3.z);
    s.w = (s0.w + s1.w) + (s2.w + s3.w);
    int q = g >> 4, dbase = (g & 15) * 4;
    *(float4*)&out[((size_t)(b * SS + q0 + q)) * DD + h * HDIM + dbase] = s;
  }
}

extern "C" void kernel_launch(void* const* d_in, const int* in_sizes, int n_in,
                              void* d_out, int out_size, void* d_ws, size_t ws_size,
                              hipStream_t stream) {
  const float* x  = (const float*)d_in[0];
  const float* wq = (const float*)d_in[1];
  const float* bq = (const float*)d_in[2];
  const float* wk = (const float*)d_in[3];
  const float* bk = (const float*)d_in[4];
  const float* wv = (const float*)d_in[5];
  const float* bv = (const float*)d_in[6];
  float* out = (float*)d_out;

  constexpr size_t XN = (size_t)BB * SS * DD;

  unsigned short* qo = (unsigned short*)d_ws;
  unsigned short* ko = qo + XN;
  unsigned short* vt = ko + XN;  // 12 MB total ws use

  proj_kernel<<<dim3(64, 8, 3), 256, 0, stream>>>(x, wq, wk, wv, bq, bk, bv, qo, ko, vt);
  attn_kernel<<<dim3(SS / 64, BB * HH), 512, 0, stream>>>(qo, ko, vt, out);
}

// Round 8
// 135.508 us; speedup vs baseline: 2.1758x; 2.1758x over previous
//
#include <hip/hip_runtime.h>
#include <cstdint>
#include <cstddef>

// Problem constants
#define BB   2
#define SS   2048
#define DD   512
#define HH   8
#define HDIM 64

typedef __attribute__((ext_vector_type(8)))  short          s16x8;
typedef __attribute__((ext_vector_type(8)))  unsigned short u16x8;
typedef __attribute__((ext_vector_type(16))) float          f32x16;

static __device__ __forceinline__ unsigned short f2bf(float f) {
  union { float f; unsigned u; } x; x.f = f;
  unsigned r = x.u + 0x7fffu + ((x.u >> 16) & 1u);  // RNE
  return (unsigned short)(r >> 16);
}
// truncating bf16 pack: result = bf(hi)<<16 | bf(lo), ONE v_perm_b32
static __device__ __forceinline__ unsigned packtrunc(float lo, float hi) {
  return __builtin_amdgcn_perm(__float_as_uint(hi), __float_as_uint(lo), 0x07060302u);
}

// sigmoid scale folded into Q: -1/sqrt(64) * log2(e)
#define QSCALE (-0.18033688011111543f)

// ---------------- fused cvt + QKV projection ---------------------------------------
// grid (M/64=64, N/64=8, 3) = 1536 blocks = 6/CU. 256 threads = 4 waves in 2x2,
// each wave 32x32 out via one 32x32x16 MFMA chain. Reg-prefetch + LDS dbuf.
// Outputs (all bf16):
//   z=0 Q: head-split [B][H][S][HD], pre-scaled by QSCALE
//   z=1 K: MFMA A-frag order:  [bh][kt=s/32][c=d/16][ lane=(d8&1)*32+(s&31) ][ j=d&7 ]
//   z=2 V: MFMA B-frag order:  [bh][kt=s/32][dh=d/32][cc=(s/16)&1][ lane=((s/8)&1)*32+(d&31) ][ j=s&7 ]
// so attn loads every fragment as ONE contiguous 1KB dwordx4 stream.
__global__ __launch_bounds__(256) void proj_kernel(
    const float* __restrict__ x,
    const float* __restrict__ wq, const float* __restrict__ wk, const float* __restrict__ wv,
    const float* __restrict__ bq, const float* __restrict__ bk, const float* __restrict__ bv,
    unsigned short* __restrict__ qo, unsigned short* __restrict__ ko,
    unsigned short* __restrict__ vt) {
  __shared__ unsigned short As[2][64 * 40];  // 64 x 32 bf16, pad->40
  __shared__ unsigned short Bs[2][64 * 40];

  const int z = blockIdx.z;
  const float* w; const float* bias;
  if (z == 0)      { w = wq; bias = bq; }
  else if (z == 1) { w = wk; bias = bk; }
  else             { w = wv; bias = bv; }

  const int t = threadIdx.x;
  const int lane = t & 63, wave = t >> 6;
  const int ln = lane & 31, hi = lane >> 5;
  const int wr = wave >> 1, wc = wave & 1;
  const int m0 = blockIdx.x * 64, n0 = blockIdx.y * 64;

  // staging: 512 float4 chunks per matrix, 2 per thread
  float4 ar[2], br[2];
#pragma unroll
  for (int i = 0; i < 2; i++) {
    int c = t + i * 256;
    ar[i] = *(const float4*)&x[(size_t)(m0 + (c >> 3)) * DD + (c & 7) * 4];
    br[i] = *(const float4*)&w[(size_t)(n0 + (c >> 3)) * DD + (c & 7) * 4];
  }
#pragma unroll
  for (int i = 0; i < 2; i++) {
    int c = t + i * 256;
    uint2 ua, ub;
    ua.x = packtrunc(ar[i].x, ar[i].y); ua.y = packtrunc(ar[i].z, ar[i].w);
    ub.x = packtrunc(br[i].x, br[i].y); ub.y = packtrunc(br[i].z, br[i].w);
    *(uint2*)&As[0][(c >> 3) * 40 + (c & 7) * 4] = ua;
    *(uint2*)&Bs[0][(c >> 3) * 40 + (c & 7) * 4] = ub;
  }
  __syncthreads();

  f32x16 acc = {};

#pragma unroll 2
  for (int kt = 0; kt < 16; kt++) {
    const int cur = kt & 1, nxt = cur ^ 1;
    if (kt < 15) {
      int k0 = (kt + 1) * 32;
#pragma unroll
      for (int i = 0; i < 2; i++) {
        int c = t + i * 256;
        ar[i] = *(const float4*)&x[(size_t)(m0 + (c >> 3)) * DD + k0 + (c & 7) * 4];
        br[i] = *(const float4*)&w[(size_t)(n0 + (c >> 3)) * DD + k0 + (c & 7) * 4];
      }
    }
#pragma unroll
    for (int c = 0; c < 2; c++) {
      s16x8 af = *(const s16x8*)&As[cur][(wr * 32 + ln) * 40 + c * 16 + hi * 8];
      s16x8 bf = *(const s16x8*)&Bs[cur][(wc * 32 + ln) * 40 + c * 16 + hi * 8];
      acc = __builtin_amdgcn_mfma_f32_32x32x16_bf16(af, bf, acc, 0, 0, 0);
    }
    if (kt < 15) {
#pragma unroll
      for (int i = 0; i < 2; i++) {
        int c = t + i * 256;
        uint2 ua, ub;
        ua.x = packtrunc(ar[i].x, ar[i].y); ua.y = packtrunc(ar[i].z, ar[i].w);
        ub.x = packtrunc(br[i].x, br[i].y); ub.y = packtrunc(br[i].z, br[i].w);
        *(uint2*)&As[nxt][(c >> 3) * 40 + (c & 7) * 4] = ua;
        *(uint2*)&Bs[nxt][(c >> 3) * 40 + (c & 7) * 4] = ub;
      }
    }
    __syncthreads();
  }

  // Epilogue. C layout: col(n) = ln, row(m) local = (r&3) + 8*(r>>2) + 4*hi.
  const int h = blockIdx.y;
  const int bidx = m0 >> 11;
  const int sbase = (m0 & 2047) + wr * 32;   // multiple of 32
  const int hd = wc * 32 + ln;
  const float bval = bias[n0 + hd];
  const size_t bhb = (size_t)(bidx * HH + h) * SS * HDIM;

  if (z == 0) {  // Q: [bh][s][hd], scaled
#pragma unroll
    for (int r = 0; r < 16; r++) {
      int s = sbase + (r & 3) + 8 * (r >> 2) + 4 * hi;
      qo[bhb + (size_t)s * HDIM + hd] = f2bf((acc[r] + bval) * QSCALE);
    }
  } else if (z == 1) {  // K fragment order
    const int c = hd >> 4, hk = (hd >> 3) & 1, j = hd & 7;
    const int kts = sbase >> 5;
    unsigned short* kd = ko + bhb + ((size_t)kts * 4 + c) * 512 + j;
#pragma unroll
    for (int r = 0; r < 16; r++) {
      int off = (r & 3) + 8 * (r >> 2) + 4 * hi;  // s & 31
      kd[(hk * 32 + off) * 8] = f2bf(acc[r] + bval);
    }
  } else {  // V fragment order; s,s+1 adjacent in j -> dword stores
    const int kts = sbase >> 5;
    unsigned short* vd = vt + bhb + ((size_t)kts * 4 + wc * 2) * 512 + ln * 8 + 4 * hi;
#pragma unroll
    for (int g = 0; g < 4; g++) {
      unsigned short* vg = vd + ((g >> 1) * 512) + (g & 1) * 256;
#pragma unroll
      for (int j = 0; j < 4; j += 2) {
        unsigned pk = (unsigned)f2bf(acc[g * 4 + j] + bval) |
                      ((unsigned)f2bf(acc[g * 4 + j + 1] + bval) << 16);
        *(unsigned*)&vg[j] = pk;
      }
    }
  }
}

// ---------------- fused sigmoid attention: 8 waves/block, frag-direct loads ---------
// grid (32, 16) = 512 blocks of 512 threads = 8 waves; block = 64 queries; each wave
// owns a key EIGHTH (8 tiles of 32, strided 8). At ~108 VGPRs the HW fits 4 waves/SIMD
// -> 2 blocks/CU = 16 waves/CU. launch_bounds (512,2): cap 256 regs/wave — the
// (512,4)=128-cap variant SPILLED (R7: 543 MB scratch writes, VGPR 64), exactly like
// R5's (256,4). Occupancy comes from actual VGPR use, not the bound.
__global__ __launch_bounds__(512, 2) void attn_kernel(
    const unsigned short* __restrict__ qb,
    const unsigned short* __restrict__ kfb,
    const unsigned short* __restrict__ vfb,
    float* __restrict__ out) {
  __shared__ __align__(16) float red[4 * 4096];  // 64 KB

  const int t = threadIdx.x;
  const int lane = t & 63, wave = t >> 6;   // wave in 0..7
  const int ln = lane & 31, hi = lane >> 5;
  // XCD swizzle: blocks of one bh all land on XCD bh%8 (16 ≡ 0 mod 8)
  const int fid = blockIdx.y * 32 + blockIdx.x;
  const int bh = fid & 15, qx = fid >> 4;
  const int b = bh >> 3, h = bh & 7;
  const unsigned short* qp = qb + (size_t)bh * SS * HDIM;
  const unsigned short* kfp = kfb + (size_t)bh * SS * HDIM;
  const unsigned short* vfp = vfb + (size_t)bh * SS * HDIM;
  const int q0 = qx * 64;

  // Q fragments (B-operand: n=q on lane, k=d), whole kernel in regs
  s16x8 qf[2][4];
#pragma unroll
  for (int qs = 0; qs < 2; qs++)
#pragma unroll
    for (int c = 0; c < 4; c++)
      qf[qs][c] = *(const s16x8*)&qp[(size_t)(q0 + qs * 32 + ln) * HDIM + c * 16 + hi * 8];

  f32x16 o00 = {}, o01 = {}, o10 = {}, o11 = {};

  // frag-ordered: chunk(kt_glob, sub) at (kt_glob*4+sub)*512 + lane*8; this wave's
  // tile i has kt_glob = i*8 + wave -> base advances 16384 per i.
  s16x8 kf[2][4], vf[2][4];
  int foff = wave * 4 * 512 + lane * 8;
#pragma unroll
  for (int c = 0; c < 4; c++) {
    kf[0][c] = *(const s16x8*)&kfp[foff + c * 512];
    vf[0][c] = *(const s16x8*)&vfp[foff + c * 512];
  }
  foff += 16384;

#pragma unroll 2
  for (int i = 0; i < 8; i++) {
    const int cur = i & 1, nxt = cur ^ 1;
    if (i < 7) {  // prefetch next tile's fragments (contiguous streams)
#pragma unroll
      for (int c = 0; c < 4; c++) {
        kf[nxt][c] = *(const s16x8*)&kfp[foff + c * 512];
        vf[nxt][c] = *(const s16x8*)&vfp[foff + c * 512];
      }
      foff += 16384;
    }

    // QK^T: S^T[key_local on (r,hi)][q on ln], two q-subtiles
    f32x16 st0 = {}, st1 = {};
#pragma unroll
    for (int c = 0; c < 4; c++) {
      st0 = __builtin_amdgcn_mfma_f32_32x32x16_bf16(kf[cur][c], qf[0][c], st0, 0, 0, 0);
      st1 = __builtin_amdgcn_mfma_f32_32x32x16_bf16(kf[cur][c], qf[1][c], st1, 0, 0, 0);
    }

    // sigmoid = rcp(1 + exp2(st)) (scale folded into Q), truncating bf16 pack
    unsigned pgx[2][4], pgy[2][4];
#pragma unroll
    for (int qs = 0; qs < 2; qs++) {
      f32x16 stq = qs ? st1 : st0;
#pragma unroll
      for (int g = 0; g < 4; g++) {
        float p0 = __builtin_amdgcn_rcpf(1.0f + __builtin_amdgcn_exp2f(stq[4 * g + 0]));
        float p1 = __builtin_amdgcn_rcpf(1.0f + __builtin_amdgcn_exp2f(stq[4 * g + 1]));
        float p2 = __builtin_amdgcn_rcpf(1.0f + __builtin_amdgcn_exp2f(stq[4 * g + 2]));
        float p3 = __builtin_amdgcn_rcpf(1.0f + __builtin_amdgcn_exp2f(stq[4 * g + 3]));
        pgx[qs][g] = packtrunc(p0, p1);
        pgy[qs][g] = packtrunc(p2, p3);
      }
    }

    // PV: A-operand P built via lane^32 exchange (validated pattern)
#pragma unroll
    for (int c = 0; c < 2; c++) {
      const int gk = 2 * c + hi, gs = 2 * c + (hi ^ 1);
#pragma unroll
      for (int qs = 0; qs < 2; qs++) {
        unsigned rx = __shfl_xor((int)pgx[qs][gs], 32, 64);
        unsigned ry = __shfl_xor((int)pgy[qs][gs], 32, 64);
        union { unsigned u[4]; s16x8 v; } pu;
        pu.u[0] = hi ? rx : pgx[qs][gk];
        pu.u[1] = hi ? ry : pgy[qs][gk];
        pu.u[2] = hi ? pgx[qs][gk] : rx;
        pu.u[3] = hi ? pgy[qs][gk] : ry;
        if (qs == 0) {
          o00 = __builtin_amdgcn_mfma_f32_32x32x16_bf16(pu.v, vf[cur][c], o00, 0, 0, 0);
          o01 = __builtin_amdgcn_mfma_f32_32x32x16_bf16(pu.v, vf[cur][2 + c], o01, 0, 0, 0);
        } else {
          o10 = __builtin_amdgcn_mfma_f32_32x32x16_bf16(pu.v, vf[cur][c], o10, 0, 0, 0);
          o11 = __builtin_amdgcn_mfma_f32_32x32x16_bf16(pu.v, vf[cur][2 + c], o11, 0, 0, 0);
        }
      }
    }
  }

  // staged 8->4->sum cross-wave O reduction in 64 KB
  if (wave >= 4) {  // waves 4..7 deposit partials in slots 0..3
#pragma unroll
    for (int qs = 0; qs < 2; qs++)
#pragma unroll
      for (int dh = 0; dh < 2; dh++) {
        f32x16 ov = qs ? (dh ? o11 : o10) : (dh ? o01 : o00);
#pragma unroll
        for (int r = 0; r < 16; r++) {
          int ql = qs * 32 + (r & 3) + 8 * (r >> 2) + 4 * hi;
          red[(wave - 4) * 4096 + ql * 64 + dh * 32 + ln] = ov[r];
        }
      }
  }
  __syncthreads();
  if (wave < 4) {  // waves 0..3 accumulate into their slot
#pragma unroll
    for (int qs = 0; qs < 2; qs++)
#pragma unroll
      for (int dh = 0; dh < 2; dh++) {
        f32x16 ov = qs ? (dh ? o11 : o10) : (dh ? o01 : o00);
#pragma unroll
        for (int r = 0; r < 16; r++) {
          int ql = qs * 32 + (r & 3) + 8 * (r >> 2) + 4 * hi;
          int idx = wave * 4096 + ql * 64 + dh * 32 + ln;
          red[idx] += ov[r];
        }
      }
  }
  __syncthreads();
  const float4* r0 = (const float4*)red;
  const float4* r1 = (const float4*)(red + 4096);
  const float4* r2 = (const float4*)(red + 8192);
  const float4* r3 = (const float4*)(red + 12288);
#pragma unroll
  for (int j = 0; j < 2; j++) {
    int g = t + j * 512;   // 1024 float4s total
    float4 s0 = r0[g], s1 = r1[g], s2 = r2[g], s3 = r3[g];
    float4 s;
    s.x = (s0.x + s1.x) + (s2.x + s3.x);
    s.y = (s0.y + s1.y) + (s2.y + s3.y);
    s.z = (s0.z + s1.z) + (s2.z + s3.z);
    s.w = (s0.w + s1.w) + (s2.w + s3.w);
    int q = g >> 4, dbase = (g & 15) * 4;
    *(float4*)&out[((size_t)(b * SS + q0 + q)) * DD + h * HDIM + dbase] = s;
  }
}

extern "C" void kernel_launch(void* const* d_in, const int* in_sizes, int n_in,
                              void* d_out, int out_size, void* d_ws, size_t ws_size,
                              hipStream_t stream) {
  const float* x  = (const float*)d_in[0];
  const float* wq = (const float*)d_in[1];
  const float* bq = (const float*)d_in[2];
  const float* wk = (const float*)d_in[3];
  const float* bk = (const float*)d_in[4];
  const float* wv = (const float*)d_in[5];
  const float* bv = (const float*)d_in[6];
  float* out = (float*)d_out;

  constexpr size_t XN = (size_t)BB * SS * DD;

  unsigned short* qo = (unsigned short*)d_ws;
  unsigned short* ko = qo + XN;
  unsigned short* vt = ko + XN;  // 12 MB total ws use

  proj_kernel<<<dim3(64, 8, 3), 256, 0, stream>>>(x, wq, wk, wv, bq, bk, bv, qo, ko, vt);
  attn_kernel<<<dim3(SS / 64, BB * HH), 512, 0, stream>>>(qo, ko, vt, out);
}

// Round 9
// 117.282 us; speedup vs baseline: 2.5139x; 1.1554x over previous
//
#include <hip/hip_runtime.h>
#include <cstdint>
#include <cstddef>

// Problem constants
#define BB   2
#define SS   2048
#define DD   512
#define HH   8
#define HDIM 64

typedef __attribute__((ext_vector_type(8)))  short          s16x8;
typedef __attribute__((ext_vector_type(16))) float          f32x16;

static __device__ __forceinline__ unsigned short f2bf(float f) {
  union { float f; unsigned u; } x; x.f = f;
  unsigned r = x.u + 0x7fffu + ((x.u >> 16) & 1u);  // RNE
  return (unsigned short)(r >> 16);
}
// truncating bf16 pack: result = bf(hi)<<16 | bf(lo), ONE v_perm_b32
static __device__ __forceinline__ unsigned packtrunc(float lo, float hi) {
  return __builtin_amdgcn_perm(__float_as_uint(hi), __float_as_uint(lo), 0x07060302u);
}

// sigmoid scale folded into Q: -1/sqrt(64) * log2(e)
#define QSCALE (-0.18033688011111543f)

// ---------------- fused cvt + QKV projection ---------------------------------------
// grid (M/64=64, N/64=8, 3) = 1536 blocks. 256 threads = 4 waves in 2x2.
// Outputs (bf16):
//   z=0 Q: head-split [B][H][S][HD], pre-scaled by QSCALE
//   z=1 K: MFMA A-frag order (physical key order)
//   z=2 V: MFMA B-frag order with the PI KEY PERMUTATION baked in:
//          logical slot l=16c+8a+e holds physical key 16c+8*(e>>2)+4a+(e&3),
//          so attn's P A-fragment is each lane's own sigmoid pairs verbatim
//          (no shfl/cndmask in the PV path).
__global__ __launch_bounds__(256) void proj_kernel(
    const float* __restrict__ x,
    const float* __restrict__ wq, const float* __restrict__ wk, const float* __restrict__ wv,
    const float* __restrict__ bq, const float* __restrict__ bk, const float* __restrict__ bv,
    unsigned short* __restrict__ qo, unsigned short* __restrict__ ko,
    unsigned short* __restrict__ vt) {
  __shared__ unsigned short As[2][64 * 40];  // 64 x 32 bf16, pad->40
  __shared__ unsigned short Bs[2][64 * 40];

  const int z = blockIdx.z;
  const float* w; const float* bias;
  if (z == 0)      { w = wq; bias = bq; }
  else if (z == 1) { w = wk; bias = bk; }
  else             { w = wv; bias = bv; }

  const int t = threadIdx.x;
  const int lane = t & 63, wave = t >> 6;
  const int ln = lane & 31, hi = lane >> 5;
  const int wr = wave >> 1, wc = wave & 1;
  const int m0 = blockIdx.x * 64, n0 = blockIdx.y * 64;

  // staging: 512 float4 chunks per matrix, 2 per thread
  float4 ar[2], br[2];
#pragma unroll
  for (int i = 0; i < 2; i++) {
    int c = t + i * 256;
    ar[i] = *(const float4*)&x[(size_t)(m0 + (c >> 3)) * DD + (c & 7) * 4];
    br[i] = *(const float4*)&w[(size_t)(n0 + (c >> 3)) * DD + (c & 7) * 4];
  }
#pragma unroll
  for (int i = 0; i < 2; i++) {
    int c = t + i * 256;
    uint2 ua, ub;
    ua.x = packtrunc(ar[i].x, ar[i].y); ua.y = packtrunc(ar[i].z, ar[i].w);
    ub.x = packtrunc(br[i].x, br[i].y); ub.y = packtrunc(br[i].z, br[i].w);
    *(uint2*)&As[0][(c >> 3) * 40 + (c & 7) * 4] = ua;
    *(uint2*)&Bs[0][(c >> 3) * 40 + (c & 7) * 4] = ub;
  }
  __syncthreads();

  f32x16 acc = {};

#pragma unroll 2
  for (int kt = 0; kt < 16; kt++) {
    const int cur = kt & 1, nxt = cur ^ 1;
    if (kt < 15) {
      int k0 = (kt + 1) * 32;
#pragma unroll
      for (int i = 0; i < 2; i++) {
        int c = t + i * 256;
        ar[i] = *(const float4*)&x[(size_t)(m0 + (c >> 3)) * DD + k0 + (c & 7) * 4];
        br[i] = *(const float4*)&w[(size_t)(n0 + (c >> 3)) * DD + k0 + (c & 7) * 4];
      }
    }
#pragma unroll
    for (int c = 0; c < 2; c++) {
      s16x8 af = *(const s16x8*)&As[cur][(wr * 32 + ln) * 40 + c * 16 + hi * 8];
      s16x8 bf = *(const s16x8*)&Bs[cur][(wc * 32 + ln) * 40 + c * 16 + hi * 8];
      acc = __builtin_amdgcn_mfma_f32_32x32x16_bf16(af, bf, acc, 0, 0, 0);
    }
    if (kt < 15) {
#pragma unroll
      for (int i = 0; i < 2; i++) {
        int c = t + i * 256;
        uint2 ua, ub;
        ua.x = packtrunc(ar[i].x, ar[i].y); ua.y = packtrunc(ar[i].z, ar[i].w);
        ub.x = packtrunc(br[i].x, br[i].y); ub.y = packtrunc(br[i].z, br[i].w);
        *(uint2*)&As[nxt][(c >> 3) * 40 + (c & 7) * 4] = ua;
        *(uint2*)&Bs[nxt][(c >> 3) * 40 + (c & 7) * 4] = ub;
      }
    }
    __syncthreads();
  }

  // Epilogue. C layout: col(n) = ln, row(m) local = (r&3) + 8*(r>>2) + 4*hi.
  const int h = blockIdx.y;
  const int bidx = m0 >> 11;
  const int sbase = (m0 & 2047) + wr * 32;   // multiple of 32
  const int hd = wc * 32 + ln;
  const float bval = bias[n0 + hd];
  const size_t bhb = (size_t)(bidx * HH + h) * SS * HDIM;

  if (z == 0) {  // Q: [bh][s][hd], scaled
#pragma unroll
    for (int r = 0; r < 16; r++) {
      int s = sbase + (r & 3) + 8 * (r >> 2) + 4 * hi;
      qo[bhb + (size_t)s * HDIM + hd] = f2bf((acc[r] + bval) * QSCALE);
    }
  } else if (z == 1) {  // K fragment order (physical keys)
    const int c = hd >> 4, hk = (hd >> 3) & 1, j = hd & 7;
    const int kts = sbase >> 5;
    unsigned short* kd = ko + bhb + ((size_t)kts * 4 + c) * 512 + j;
#pragma unroll
    for (int r = 0; r < 16; r++) {
      int off = (r & 3) + 8 * (r >> 2) + 4 * hi;  // s & 31
      kd[(hk * 32 + off) * 8] = f2bf(acc[r] + bval);
    }
  } else {  // V fragment order WITH pi permutation: physical key kappa=8g+4hi+j
            // stored at chunk (g>>1), k-half bit=hi, element e=4*(g&1)+j.
    const int kts = sbase >> 5;
    unsigned short* vd = vt + bhb + ((size_t)kts * 4 + wc * 2) * 512 + hi * 256 + ln * 8;
#pragma unroll
    for (int g = 0; g < 4; g++) {
      unsigned short* vg = vd + (g >> 1) * 512 + (g & 1) * 4;
#pragma unroll
      for (int j = 0; j < 4; j += 2) {
        unsigned pk = (unsigned)f2bf(acc[g * 4 + j] + bval) |
                      ((unsigned)f2bf(acc[g * 4 + j + 1] + bval) << 16);
        *(unsigned*)&vg[j] = pk;
      }
    }
  }
}

// ---------------- fused sigmoid attention: 32q blocks, pi-layout, no shfl -----------
// grid (S/32=64, B*H=16) = 1024 blocks of 256 threads = 4 waves; block = 32 queries;
// each wave owns a key QUARTER (16 tiles of 32, strided 4). K/V fragments contiguous
// 1KB dwordx4 loads, register double-buffered, zero barriers in the loop. P enters
// PV as each lane's own packed sigmoid pairs (pi-permuted V — no shfl/cndmask).
// ~152 unified regs/wave -> 3 waves/SIMD -> 3 blocks/CU (R8 was reg-capped at 2).
__global__ __launch_bounds__(256, 2) void attn_kernel(
    const unsigned short* __restrict__ qb,
    const unsigned short* __restrict__ kfb,
    const unsigned short* __restrict__ vfb,
    float* __restrict__ out) {
  __shared__ __align__(16) float red[2][2048];  // 16 KB

  const int t = threadIdx.x;
  const int lane = t & 63, wave = t >> 6;   // wave in 0..3
  const int ln = lane & 31, hi = lane >> 5;
  // XCD swizzle: blocks of one bh all land on XCD bh%8 (16 ≡ 0 mod 8)
  const int fid = blockIdx.y * 64 + blockIdx.x;
  const int bh = fid & 15, qx = fid >> 4;
  const int b = bh >> 3, h = bh & 7;
  const unsigned short* qp = qb + (size_t)bh * SS * HDIM;
  const unsigned short* kfp = kfb + (size_t)bh * SS * HDIM;
  const unsigned short* vfp = vfb + (size_t)bh * SS * HDIM;
  const int q0 = qx * 32;

  // Q fragments (B-operand: n=q on lane, k=d), whole kernel in regs
  s16x8 qf[4];
#pragma unroll
  for (int c = 0; c < 4; c++)
    qf[c] = *(const s16x8*)&qp[(size_t)(q0 + ln) * HDIM + c * 16 + hi * 8];

  f32x16 o0 = {}, o1 = {};

  // frag-ordered: chunk(kt_glob, sub) at (kt_glob*4+sub)*512 + lane*8; this wave's
  // tile i has kt_glob = i*4 + wave -> base advances 8192 per i.
  s16x8 kf[2][4], vf[2][4];
  int foff = wave * 4 * 512 + lane * 8;
#pragma unroll
  for (int c = 0; c < 4; c++) {
    kf[0][c] = *(const s16x8*)&kfp[foff + c * 512];
    vf[0][c] = *(const s16x8*)&vfp[foff + c * 512];
  }
  foff += 8192;

#pragma unroll 2
  for (int i = 0; i < 16; i++) {
    const int cur = i & 1, nxt = cur ^ 1;
    if (i < 15) {  // prefetch next tile's fragments (contiguous streams)
#pragma unroll
      for (int c = 0; c < 4; c++) {
        kf[nxt][c] = *(const s16x8*)&kfp[foff + c * 512];
        vf[nxt][c] = *(const s16x8*)&vfp[foff + c * 512];
      }
      foff += 8192;
    }

    // QK^T: S^T[physical key on (r,hi)][q on ln]
    f32x16 st = {};
#pragma unroll
    for (int c = 0; c < 4; c++)
      st = __builtin_amdgcn_mfma_f32_32x32x16_bf16(kf[cur][c], qf[c], st, 0, 0, 0);

    // sigmoid = rcp(1 + exp2(st)) (scale folded into Q), truncating bf16 pack.
    // pg[2g]   = physical keys (8g+4hi+0, 8g+4hi+1)
    // pg[2g+1] = physical keys (8g+4hi+2, 8g+4hi+3)
    unsigned pg[8];
#pragma unroll
    for (int g = 0; g < 4; g++) {
      float p0 = __builtin_amdgcn_rcpf(1.0f + __builtin_amdgcn_exp2f(st[4 * g + 0]));
      float p1 = __builtin_amdgcn_rcpf(1.0f + __builtin_amdgcn_exp2f(st[4 * g + 1]));
      float p2 = __builtin_amdgcn_rcpf(1.0f + __builtin_amdgcn_exp2f(st[4 * g + 2]));
      float p3 = __builtin_amdgcn_rcpf(1.0f + __builtin_amdgcn_exp2f(st[4 * g + 3]));
      pg[2 * g]     = packtrunc(p0, p1);
      pg[2 * g + 1] = packtrunc(p2, p3);
    }

    // PV: with the pi-permuted V layout, the A-operand for key chunk c is
    // pg[4c..4c+3] verbatim (this lane's own pairs) — no cross-lane exchange.
#pragma unroll
    for (int c = 0; c < 2; c++) {
      union { unsigned u[4]; s16x8 v; } pu;
      pu.u[0] = pg[4 * c + 0];
      pu.u[1] = pg[4 * c + 1];
      pu.u[2] = pg[4 * c + 2];
      pu.u[3] = pg[4 * c + 3];
      o0 = __builtin_amdgcn_mfma_f32_32x32x16_bf16(pu.v, vf[cur][c], o0, 0, 0, 0);
      o1 = __builtin_amdgcn_mfma_f32_32x32x16_bf16(pu.v, vf[cur][2 + c], o1, 0, 0, 0);
    }
  }

  // staged 4->2->sum cross-wave O reduction in 16 KB
  if (wave >= 2) {
#pragma unroll
    for (int dh = 0; dh < 2; dh++) {
      f32x16 ov = dh ? o1 : o0;
#pragma unroll
      for (int r = 0; r < 16; r++) {
        int ql = (r & 3) + 8 * (r >> 2) + 4 * hi;
        red[wave - 2][ql * 64 + dh * 32 + ln] = ov[r];
      }
    }
  }
  __syncthreads();
  if (wave < 2) {
#pragma unroll
    for (int dh = 0; dh < 2; dh++) {
      f32x16 ov = dh ? o1 : o0;
#pragma unroll
      for (int r = 0; r < 16; r++) {
        int ql = (r & 3) + 8 * (r >> 2) + 4 * hi;
        red[wave][ql * 64 + dh * 32 + ln] += ov[r];
      }
    }
  }
  __syncthreads();
  const float4* r0 = (const float4*)&red[0][0];
  const float4* r1 = (const float4*)&red[1][0];
#pragma unroll
  for (int j = 0; j < 2; j++) {
    int g = t + j * 256;   // 512 float4s total
    float4 s0 = r0[g], s1 = r1[g];
    float4 s;
    s.x = s0.x + s1.x; s.y = s0.y + s1.y; s.z = s0.z + s1.z; s.w = s0.w + s1.w;
    int q = g >> 4, dbase = (g & 15) * 4;
    *(float4*)&out[((size_t)(b * SS + q0 + q)) * DD + h * HDIM + dbase] = s;
  }
}

extern "C" void kernel_launch(void* const* d_in, const int* in_sizes, int n_in,
                              void* d_out, int out_size, void* d_ws, size_t ws_size,
                              hipStream_t stream) {
  const float* x  = (const float*)d_in[0];
  const float* wq = (const float*)d_in[1];
  const float* bq = (const float*)d_in[2];
  const float* wk = (const float*)d_in[3];
  const float* bk = (const float*)d_in[4];
  const float* wv = (const float*)d_in[5];
  const float* bv = (const float*)d_in[6];
  float* out = (float*)d_out;

  constexpr size_t XN = (size_t)BB * SS * DD;

  unsigned short* qo = (unsigned short*)d_ws;
  unsigned short* ko = qo + XN;
  unsigned short* vt = ko + XN;  // 12 MB total ws use

  proj_kernel<<<dim3(64, 8, 3), 256, 0, stream>>>(x, wq, wk, wv, bq, bk, bv, qo, ko, vt);
  attn_kernel<<<dim3(SS / 32, BB * HH), 256, 0, stream>>>(qo, ko, vt, out);
}

// Round 10
// 116.092 us; speedup vs baseline: 2.5397x; 1.0103x over previous
//
#include <hip/hip_runtime.h>
#include <cstdint>
#include <cstddef>

// Problem constants
#define BB   2
#define SS   2048
#define DD   512
#define HH   8
#define HDIM 64

typedef __attribute__((ext_vector_type(8)))  short          s16x8;
typedef __attribute__((ext_vector_type(16))) float          f32x16;

static __device__ __forceinline__ unsigned short f2bf(float f) {
  union { float f; unsigned u; } x; x.f = f;
  unsigned r = x.u + 0x7fffu + ((x.u >> 16) & 1u);  // RNE
  return (unsigned short)(r >> 16);
}
// truncating bf16 pack: result = bf(hi)<<16 | bf(lo), ONE v_perm_b32
static __device__ __forceinline__ unsigned packtrunc(float lo, float hi) {
  return __builtin_amdgcn_perm(__float_as_uint(hi), __float_as_uint(lo), 0x07060302u);
}

// sigmoid scale folded into Q: -1/sqrt(64) * log2(e)
#define QSCALE (-0.18033688011111543f)

// ---------------- fused cvt + QKV projection ---------------------------------------
// grid (M/64=64, N/64=8, 3) = 1536 blocks. 256 threads = 4 waves in 2x2.
// Outputs (bf16):
//   z=0 Q: head-split [B][H][S][HD], pre-scaled by QSCALE
//   z=1 K: MFMA A-frag order (physical key order)
//   z=2 V: MFMA B-frag order with the PI KEY PERMUTATION baked in:
//          logical slot l=16c+8a+e holds physical key 16c+8*(e>>2)+4a+(e&3),
//          so attn's P A-fragment is each lane's own sigmoid pairs verbatim
//          (no shfl/cndmask in the PV path).
__global__ __launch_bounds__(256) void proj_kernel(
    const float* __restrict__ x,
    const float* __restrict__ wq, const float* __restrict__ wk, const float* __restrict__ wv,
    const float* __restrict__ bq, const float* __restrict__ bk, const float* __restrict__ bv,
    unsigned short* __restrict__ qo, unsigned short* __restrict__ ko,
    unsigned short* __restrict__ vt) {
  __shared__ unsigned short As[2][64 * 40];  // 64 x 32 bf16, pad->40
  __shared__ unsigned short Bs[2][64 * 40];

  const int z = blockIdx.z;
  const float* w; const float* bias;
  if (z == 0)      { w = wq; bias = bq; }
  else if (z == 1) { w = wk; bias = bk; }
  else             { w = wv; bias = bv; }

  const int t = threadIdx.x;
  const int lane = t & 63, wave = t >> 6;
  const int ln = lane & 31, hi = lane >> 5;
  const int wr = wave >> 1, wc = wave & 1;
  const int m0 = blockIdx.x * 64, n0 = blockIdx.y * 64;

  // staging: 512 float4 chunks per matrix, 2 per thread
  float4 ar[2], br[2];
#pragma unroll
  for (int i = 0; i < 2; i++) {
    int c = t + i * 256;
    ar[i] = *(const float4*)&x[(size_t)(m0 + (c >> 3)) * DD + (c & 7) * 4];
    br[i] = *(const float4*)&w[(size_t)(n0 + (c >> 3)) * DD + (c & 7) * 4];
  }
#pragma unroll
  for (int i = 0; i < 2; i++) {
    int c = t + i * 256;
    uint2 ua, ub;
    ua.x = packtrunc(ar[i].x, ar[i].y); ua.y = packtrunc(ar[i].z, ar[i].w);
    ub.x = packtrunc(br[i].x, br[i].y); ub.y = packtrunc(br[i].z, br[i].w);
    *(uint2*)&As[0][(c >> 3) * 40 + (c & 7) * 4] = ua;
    *(uint2*)&Bs[0][(c >> 3) * 40 + (c & 7) * 4] = ub;
  }
  __syncthreads();

  f32x16 acc = {};

#pragma unroll 2
  for (int kt = 0; kt < 16; kt++) {
    const int cur = kt & 1, nxt = cur ^ 1;
    if (kt < 15) {
      int k0 = (kt + 1) * 32;
#pragma unroll
      for (int i = 0; i < 2; i++) {
        int c = t + i * 256;
        ar[i] = *(const float4*)&x[(size_t)(m0 + (c >> 3)) * DD + k0 + (c & 7) * 4];
        br[i] = *(const float4*)&w[(size_t)(n0 + (c >> 3)) * DD + k0 + (c & 7) * 4];
      }
    }
#pragma unroll
    for (int c = 0; c < 2; c++) {
      s16x8 af = *(const s16x8*)&As[cur][(wr * 32 + ln) * 40 + c * 16 + hi * 8];
      s16x8 bf = *(const s16x8*)&Bs[cur][(wc * 32 + ln) * 40 + c * 16 + hi * 8];
      acc = __builtin_amdgcn_mfma_f32_32x32x16_bf16(af, bf, acc, 0, 0, 0);
    }
    if (kt < 15) {
#pragma unroll
      for (int i = 0; i < 2; i++) {
        int c = t + i * 256;
        uint2 ua, ub;
        ua.x = packtrunc(ar[i].x, ar[i].y); ua.y = packtrunc(ar[i].z, ar[i].w);
        ub.x = packtrunc(br[i].x, br[i].y); ub.y = packtrunc(br[i].z, br[i].w);
        *(uint2*)&As[nxt][(c >> 3) * 40 + (c & 7) * 4] = ua;
        *(uint2*)&Bs[nxt][(c >> 3) * 40 + (c & 7) * 4] = ub;
      }
    }
    __syncthreads();
  }

  // Epilogue. C layout: col(n) = ln, row(m) local = (r&3) + 8*(r>>2) + 4*hi.
  const int h = blockIdx.y;
  const int bidx = m0 >> 11;
  const int sbase = (m0 & 2047) + wr * 32;   // multiple of 32
  const int hd = wc * 32 + ln;
  const float bval = bias[n0 + hd];
  const size_t bhb = (size_t)(bidx * HH + h) * SS * HDIM;

  if (z == 0) {  // Q: [bh][s][hd], scaled
#pragma unroll
    for (int r = 0; r < 16; r++) {
      int s = sbase + (r & 3) + 8 * (r >> 2) + 4 * hi;
      qo[bhb + (size_t)s * HDIM + hd] = f2bf((acc[r] + bval) * QSCALE);
    }
  } else if (z == 1) {  // K fragment order (physical keys)
    const int c = hd >> 4, hk = (hd >> 3) & 1, j = hd & 7;
    const int kts = sbase >> 5;
    unsigned short* kd = ko + bhb + ((size_t)kts * 4 + c) * 512 + j;
#pragma unroll
    for (int r = 0; r < 16; r++) {
      int off = (r & 3) + 8 * (r >> 2) + 4 * hi;  // s & 31
      kd[(hk * 32 + off) * 8] = f2bf(acc[r] + bval);
    }
  } else {  // V fragment order WITH pi permutation: physical key kappa=8g+4hi+j
            // stored at chunk (g>>1), k-half bit=hi, element e=4*(g&1)+j.
    const int kts = sbase >> 5;
    unsigned short* vd = vt + bhb + ((size_t)kts * 4 + wc * 2) * 512 + hi * 256 + ln * 8;
#pragma unroll
    for (int g = 0; g < 4; g++) {
      unsigned short* vg = vd + (g >> 1) * 512 + (g & 1) * 4;
#pragma unroll
      for (int j = 0; j < 4; j += 2) {
        unsigned pk = (unsigned)f2bf(acc[g * 4 + j] + bval) |
                      ((unsigned)f2bf(acc[g * 4 + j + 1] + bval) << 16);
        *(unsigned*)&vg[j] = pk;
      }
    }
  }
}

// ---------------- fused sigmoid attention: 8-wave 64q blocks, rotated frags ---------
// grid (S/64=32, B*H=16) = 512 blocks of 512 threads = 8 waves = (qh,kh) 2x4 split:
// 32 queries x key-quarter (16 tiles of 32) per wave. K/V fragments contiguous 1KB
// dwordx4 loads, SINGLE-buffered with manual rotation: kf dies after QK^T -> reload
// in place (covered by sigmoid+PV); vf dies after PV -> reload (covered by next
// QK+sigmoid). ~115 regs/wave -> 4 waves/SIMD at 16 waves/CU. pi-permuted V:
// P A-fragment = lane's own sigmoid pairs, no cross-lane ops. Zero loop barriers.
__global__ __launch_bounds__(512, 2) void attn_kernel(
    const unsigned short* __restrict__ qb,
    const unsigned short* __restrict__ kfb,
    const unsigned short* __restrict__ vfb,
    float* __restrict__ out) {
  __shared__ __align__(16) float red[2 * 4096];  // 32 KB, 2 reduction slots

  const int t = threadIdx.x;
  const int lane = t & 63, wave = t >> 6;   // wave 0..7
  const int ln = lane & 31, hi = lane >> 5;
  const int qh = wave & 1, kh = wave >> 1;  // qh: 32q half, kh: key quarter
  // XCD swizzle: blocks of one bh all land on XCD bh%8 (16 ≡ 0 mod 8)
  const int fid = blockIdx.y * 32 + blockIdx.x;
  const int bh = fid & 15, qx = fid >> 4;
  const int b = bh >> 3, h = bh & 7;
  const unsigned short* qp = qb + (size_t)bh * SS * HDIM;
  const unsigned short* kfp = kfb + (size_t)bh * SS * HDIM;
  const unsigned short* vfp = vfb + (size_t)bh * SS * HDIM;
  const int q0 = qx * 64;

  // Q fragments (B-operand: n=q on lane, k=d), whole kernel in regs
  s16x8 qf[4];
#pragma unroll
  for (int c = 0; c < 4; c++)
    qf[c] = *(const s16x8*)&qp[(size_t)(q0 + qh * 32 + ln) * HDIM + c * 16 + hi * 8];

  f32x16 o0 = {}, o1 = {};

  // frag-ordered: tile kt_glob at kt_glob*2048 + c*512 + lane*8.
  // This wave: kt_glob = kh*16 + i, i in 0..15.
  s16x8 kf[4], vf[4];
  int foff = kh * 16 * 2048 + lane * 8;
#pragma unroll
  for (int c = 0; c < 4; c++) {
    kf[c] = *(const s16x8*)&kfp[foff + c * 512];
    vf[c] = *(const s16x8*)&vfp[foff + c * 512];
  }
  foff += 2048;

#pragma unroll 1
  for (int i = 0; i < 16; i++) {
    // QK^T: S^T[physical key on (r,hi)][q on ln]
    f32x16 st = {};
#pragma unroll
    for (int c = 0; c < 4; c++)
      st = __builtin_amdgcn_mfma_f32_32x32x16_bf16(kf[c], qf[c], st, 0, 0, 0);

    // kf is dead -> rotate in next tile's K (latency covered by sigmoid+PV)
    if (i < 15) {
#pragma unroll
      for (int c = 0; c < 4; c++)
        kf[c] = *(const s16x8*)&kfp[foff + c * 512];
    }

    // sigmoid = rcp(1 + exp2(st)) (scale folded into Q), truncating bf16 pack.
    unsigned pg[8];
#pragma unroll
    for (int g = 0; g < 4; g++) {
      float p0 = __builtin_amdgcn_rcpf(1.0f + __builtin_amdgcn_exp2f(st[4 * g + 0]));
      float p1 = __builtin_amdgcn_rcpf(1.0f + __builtin_amdgcn_exp2f(st[4 * g + 1]));
      float p2 = __builtin_amdgcn_rcpf(1.0f + __builtin_amdgcn_exp2f(st[4 * g + 2]));
      float p3 = __builtin_amdgcn_rcpf(1.0f + __builtin_amdgcn_exp2f(st[4 * g + 3]));
      pg[2 * g]     = packtrunc(p0, p1);
      pg[2 * g + 1] = packtrunc(p2, p3);
    }

    // PV: pi-permuted V -> A-operand is pg[4c..4c+3] verbatim
#pragma unroll
    for (int c = 0; c < 2; c++) {
      union { unsigned u[4]; s16x8 v; } pu;
      pu.u[0] = pg[4 * c + 0];
      pu.u[1] = pg[4 * c + 1];
      pu.u[2] = pg[4 * c + 2];
      pu.u[3] = pg[4 * c + 3];
      o0 = __builtin_amdgcn_mfma_f32_32x32x16_bf16(pu.v, vf[c], o0, 0, 0, 0);
      o1 = __builtin_amdgcn_mfma_f32_32x32x16_bf16(pu.v, vf[2 + c], o1, 0, 0, 0);
    }

    // vf is dead -> rotate in next tile's V (latency covered by next QK+sigmoid)
    if (i < 15) {
#pragma unroll
      for (int c = 0; c < 4; c++)
        vf[c] = *(const s16x8*)&vfp[foff + c * 512];
      foff += 2048;
    }
  }

  // staged 4-way kh reduction in 2 slots: kh{2,3} store -> kh{0,1} add -> pairwise sum
  if (kh >= 2) {
    const int slot = kh - 2;
#pragma unroll
    for (int dh = 0; dh < 2; dh++) {
      f32x16 ov = dh ? o1 : o0;
#pragma unroll
      for (int r = 0; r < 16; r++) {
        int ql = (r & 3) + 8 * (r >> 2) + 4 * hi;
        red[slot * 4096 + (qh * 32 + ql) * 64 + dh * 32 + ln] = ov[r];
      }
    }
  }
  __syncthreads();
  if (kh < 2) {
#pragma unroll
    for (int dh = 0; dh < 2; dh++) {
      f32x16 ov = dh ? o1 : o0;
#pragma unroll
      for (int r = 0; r < 16; r++) {
        int ql = (r & 3) + 8 * (r >> 2) + 4 * hi;
        red[kh * 4096 + (qh * 32 + ql) * 64 + dh * 32 + ln] += ov[r];
      }
    }
  }
  __syncthreads();
  const float4* r0 = (const float4*)red;
  const float4* r1 = (const float4*)(red + 4096);
#pragma unroll
  for (int j = 0; j < 2; j++) {
    int g = t + j * 512;   // 1024 float4s total (64q x 64d)
    float4 s0 = r0[g], s1 = r1[g];
    float4 s;
    s.x = s0.x + s1.x; s.y = s0.y + s1.y; s.z = s0.z + s1.z; s.w = s0.w + s1.w;
    int q = g >> 4, dbase = (g & 15) * 4;
    *(float4*)&out[((size_t)(b * SS + q0 + q)) * DD + h * HDIM + dbase] = s;
  }
}

extern "C" void kernel_launch(void* const* d_in, const int* in_sizes, int n_in,
                              void* d_out, int out_size, void* d_ws, size_t ws_size,
                              hipStream_t stream) {
  const float* x  = (const float*)d_in[0];
  const float* wq = (const float*)d_in[1];
  const float* bq = (const float*)d_in[2];
  const float* wk = (const float*)d_in[3];
  const float* bk = (const float*)d_in[4];
  const float* wv = (const float*)d_in[5];
  const float* bv = (const float*)d_in[6];
  float* out = (float*)d_out;

  constexpr size_t XN = (size_t)BB * SS * DD;

  unsigned short* qo = (unsigned short*)d_ws;
  unsigned short* ko = qo + XN;
  unsigned short* vt = ko + XN;  // 12 MB total ws use

  proj_kernel<<<dim3(64, 8, 3), 256, 0, stream>>>(x, wq, wk, wv, bq, bk, bv, qo, ko, vt);
  attn_kernel<<<dim3(SS / 64, BB * HH), 512, 0, stream>>>(qo, ko, vt, out);
}

// Round 11
// 114.538 us; speedup vs baseline: 2.5741x; 1.0136x over previous
//
#include <hip/hip_runtime.h>
#include <cstdint>
#include <cstddef>

// Problem constants
#define BB   2
#define SS   2048
#define DD   512
#define HH   8
#define HDIM 64

typedef __attribute__((ext_vector_type(8)))  short          s16x8;
typedef __attribute__((ext_vector_type(16))) float          f32x16;

static __device__ __forceinline__ unsigned short f2bf(float f) {
  union { float f; unsigned u; } x; x.f = f;
  unsigned r = x.u + 0x7fffu + ((x.u >> 16) & 1u);  // RNE
  return (unsigned short)(r >> 16);
}
// truncating bf16 pack: result = bf(hi)<<16 | bf(lo), ONE v_perm_b32
static __device__ __forceinline__ unsigned packtrunc(float lo, float hi) {
  return __builtin_amdgcn_perm(__float_as_uint(hi), __float_as_uint(lo), 0x07060302u);
}

// sigmoid scale folded into Q: -1/sqrt(64) * log2(e)
#define QSCALE (-0.18033688011111543f)

// ---------------- fused cvt + QKV projection ---------------------------------------
// grid (M/64=64, N/64=8, 3) = 1536 blocks. 256 threads = 4 waves in 2x2.
// Outputs (bf16):
//   z=0 Q: head-split [B][H][S][HD], pre-scaled by QSCALE
//   z=1 K: MFMA A-frag order (physical key order)
//   z=2 V: MFMA B-frag order with the PI KEY PERMUTATION baked in:
//          logical slot l=16c+8a+e holds physical key 16c+8*(e>>2)+4a+(e&3),
//          so attn's P A-fragment is each lane's own sigmoid pairs verbatim
//          (no shfl/cndmask in the PV path).
__global__ __launch_bounds__(256) void proj_kernel(
    const float* __restrict__ x,
    const float* __restrict__ wq, const float* __restrict__ wk, const float* __restrict__ wv,
    const float* __restrict__ bq, const float* __restrict__ bk, const float* __restrict__ bv,
    unsigned short* __restrict__ qo, unsigned short* __restrict__ ko,
    unsigned short* __restrict__ vt) {
  __shared__ unsigned short As[2][64 * 40];  // 64 x 32 bf16, pad->40
  __shared__ unsigned short Bs[2][64 * 40];

  const int z = blockIdx.z;
  const float* w; const float* bias;
  if (z == 0)      { w = wq; bias = bq; }
  else if (z == 1) { w = wk; bias = bk; }
  else             { w = wv; bias = bv; }

  const int t = threadIdx.x;
  const int lane = t & 63, wave = t >> 6;
  const int ln = lane & 31, hi = lane >> 5;
  const int wr = wave >> 1, wc = wave & 1;
  const int m0 = blockIdx.x * 64, n0 = blockIdx.y * 64;

  // staging: 512 float4 chunks per matrix, 2 per thread
  float4 ar[2], br[2];
#pragma unroll
  for (int i = 0; i < 2; i++) {
    int c = t + i * 256;
    ar[i] = *(const float4*)&x[(size_t)(m0 + (c >> 3)) * DD + (c & 7) * 4];
    br[i] = *(const float4*)&w[(size_t)(n0 + (c >> 3)) * DD + (c & 7) * 4];
  }
#pragma unroll
  for (int i = 0; i < 2; i++) {
    int c = t + i * 256;
    uint2 ua, ub;
    ua.x = packtrunc(ar[i].x, ar[i].y); ua.y = packtrunc(ar[i].z, ar[i].w);
    ub.x = packtrunc(br[i].x, br[i].y); ub.y = packtrunc(br[i].z, br[i].w);
    *(uint2*)&As[0][(c >> 3) * 40 + (c & 7) * 4] = ua;
    *(uint2*)&Bs[0][(c >> 3) * 40 + (c & 7) * 4] = ub;
  }
  __syncthreads();

  f32x16 acc = {};

#pragma unroll 2
  for (int kt = 0; kt < 16; kt++) {
    const int cur = kt & 1, nxt = cur ^ 1;
    if (kt < 15) {
      int k0 = (kt + 1) * 32;
#pragma unroll
      for (int i = 0; i < 2; i++) {
        int c = t + i * 256;
        ar[i] = *(const float4*)&x[(size_t)(m0 + (c >> 3)) * DD + k0 + (c & 7) * 4];
        br[i] = *(const float4*)&w[(size_t)(n0 + (c >> 3)) * DD + k0 + (c & 7) * 4];
      }
    }
#pragma unroll
    for (int c = 0; c < 2; c++) {
      s16x8 af = *(const s16x8*)&As[cur][(wr * 32 + ln) * 40 + c * 16 + hi * 8];
      s16x8 bf = *(const s16x8*)&Bs[cur][(wc * 32 + ln) * 40 + c * 16 + hi * 8];
      acc = __builtin_amdgcn_mfma_f32_32x32x16_bf16(af, bf, acc, 0, 0, 0);
    }
    if (kt < 15) {
#pragma unroll
      for (int i = 0; i < 2; i++) {
        int c = t + i * 256;
        uint2 ua, ub;
        ua.x = packtrunc(ar[i].x, ar[i].y); ua.y = packtrunc(ar[i].z, ar[i].w);
        ub.x = packtrunc(br[i].x, br[i].y); ub.y = packtrunc(br[i].z, br[i].w);
        *(uint2*)&As[nxt][(c >> 3) * 40 + (c & 7) * 4] = ua;
        *(uint2*)&Bs[nxt][(c >> 3) * 40 + (c & 7) * 4] = ub;
      }
    }
    __syncthreads();
  }

  // Epilogue. C layout: col(n) = ln, row(m) local = (r&3) + 8*(r>>2) + 4*hi.
  const int h = blockIdx.y;
  const int bidx = m0 >> 11;
  const int sbase = (m0 & 2047) + wr * 32;   // multiple of 32
  const int hd = wc * 32 + ln;
  const float bval = bias[n0 + hd];
  const size_t bhb = (size_t)(bidx * HH + h) * SS * HDIM;

  if (z == 0) {  // Q: [bh][s][hd], scaled
#pragma unroll
    for (int r = 0; r < 16; r++) {
      int s = sbase + (r & 3) + 8 * (r >> 2) + 4 * hi;
      qo[bhb + (size_t)s * HDIM + hd] = f2bf((acc[r] + bval) * QSCALE);
    }
  } else if (z == 1) {  // K fragment order (physical keys)
    const int c = hd >> 4, hk = (hd >> 3) & 1, j = hd & 7;
    const int kts = sbase >> 5;
    unsigned short* kd = ko + bhb + ((size_t)kts * 4 + c) * 512 + j;
#pragma unroll
    for (int r = 0; r < 16; r++) {
      int off = (r & 3) + 8 * (r >> 2) + 4 * hi;  // s & 31
      kd[(hk * 32 + off) * 8] = f2bf(acc[r] + bval);
    }
  } else {  // V fragment order WITH pi permutation: physical key kappa=8g+4hi+j
            // stored at chunk (g>>1), k-half bit=hi, element e=4*(g&1)+j.
    const int kts = sbase >> 5;
    unsigned short* vd = vt + bhb + ((size_t)kts * 4 + wc * 2) * 512 + hi * 256 + ln * 8;
#pragma unroll
    for (int g = 0; g < 4; g++) {
      unsigned short* vg = vd + (g >> 1) * 512 + (g & 1) * 4;
#pragma unroll
      for (int j = 0; j < 4; j += 2) {
        unsigned pk = (unsigned)f2bf(acc[g * 4 + j] + bval) |
                      ((unsigned)f2bf(acc[g * 4 + j + 1] + bval) << 16);
        *(unsigned*)&vg[j] = pk;
      }
    }
  }
}

// ---------------- fused sigmoid attention: 8-wave 64q blocks, rotated frags ---------
// grid (S/64=32, B*H=16) = 512 blocks of 512 threads = 8 waves = (qh,kh) 2x4 split:
// 32 queries x key-quarter (16 tiles of 32) per wave. K/V fragments contiguous 1KB
// dwordx4 loads, SINGLE-buffered with manual rotation: kf dies after QK^T -> reload
// in place; vf dies after PV -> reload. pi-permuted V: P A-fragment = lane's own
// sigmoid pairs, no cross-lane ops. Zero loop barriers.
// launch_bounds (512,4): cap 128 unified regs -> 4 waves/SIMD GUARANTEED. Body now
// fits (~84 VGPR + 32 acc = 116): R5/R7 spilled because double-buffered frags +
// 64 acc could never fit 128; single-buffer + 32 acc can. Watch WRITE_SIZE: ~8 MB
// = no spill, 100+ MB = spill -> revert to (512,2).
__global__ __launch_bounds__(512, 4) void attn_kernel(
    const unsigned short* __restrict__ qb,
    const unsigned short* __restrict__ kfb,
    const unsigned short* __restrict__ vfb,
    float* __restrict__ out) {
  __shared__ __align__(16) float red[2 * 4096];  // 32 KB, 2 reduction slots

  const int t = threadIdx.x;
  const int lane = t & 63, wave = t >> 6;   // wave 0..7
  const int ln = lane & 31, hi = lane >> 5;
  const int qh = wave & 1, kh = wave >> 1;  // qh: 32q half, kh: key quarter
  // XCD swizzle: blocks of one bh all land on XCD bh%8 (16 ≡ 0 mod 8)
  const int fid = blockIdx.y * 32 + blockIdx.x;
  const int bh = fid & 15, qx = fid >> 4;
  const int b = bh >> 3, h = bh & 7;
  const unsigned short* qp = qb + (size_t)bh * SS * HDIM;
  const unsigned short* kfp = kfb + (size_t)bh * SS * HDIM;
  const unsigned short* vfp = vfb + (size_t)bh * SS * HDIM;
  const int q0 = qx * 64;

  // Q fragments (B-operand: n=q on lane, k=d), whole kernel in regs
  s16x8 qf[4];
#pragma unroll
  for (int c = 0; c < 4; c++)
    qf[c] = *(const s16x8*)&qp[(size_t)(q0 + qh * 32 + ln) * HDIM + c * 16 + hi * 8];

  f32x16 o0 = {}, o1 = {};

  // frag-ordered: tile kt_glob at kt_glob*2048 + c*512 + lane*8.
  // This wave: kt_glob = kh*16 + i, i in 0..15.
  s16x8 kf[4], vf[4];
  int foff = kh * 16 * 2048 + lane * 8;
#pragma unroll
  for (int c = 0; c < 4; c++) {
    kf[c] = *(const s16x8*)&kfp[foff + c * 512];
    vf[c] = *(const s16x8*)&vfp[foff + c * 512];
  }
  foff += 2048;

#pragma unroll 1
  for (int i = 0; i < 16; i++) {
    // QK^T: S^T[physical key on (r,hi)][q on ln]
    f32x16 st = {};
#pragma unroll
    for (int c = 0; c < 4; c++)
      st = __builtin_amdgcn_mfma_f32_32x32x16_bf16(kf[c], qf[c], st, 0, 0, 0);

    // kf is dead -> rotate in next tile's K (latency covered by sigmoid+PV)
    if (i < 15) {
#pragma unroll
      for (int c = 0; c < 4; c++)
        kf[c] = *(const s16x8*)&kfp[foff + c * 512];
    }

    // sigmoid = rcp(1 + exp2(st)) (scale folded into Q), truncating bf16 pack.
    unsigned pg[8];
#pragma unroll
    for (int g = 0; g < 4; g++) {
      float p0 = __builtin_amdgcn_rcpf(1.0f + __builtin_amdgcn_exp2f(st[4 * g + 0]));
      float p1 = __builtin_amdgcn_rcpf(1.0f + __builtin_amdgcn_exp2f(st[4 * g + 1]));
      float p2 = __builtin_amdgcn_rcpf(1.0f + __builtin_amdgcn_exp2f(st[4 * g + 2]));
      float p3 = __builtin_amdgcn_rcpf(1.0f + __builtin_amdgcn_exp2f(st[4 * g + 3]));
      pg[2 * g]     = packtrunc(p0, p1);
      pg[2 * g + 1] = packtrunc(p2, p3);
    }

    // PV: pi-permuted V -> A-operand is pg[4c..4c+3] verbatim
#pragma unroll
    for (int c = 0; c < 2; c++) {
      union { unsigned u[4]; s16x8 v; } pu;
      pu.u[0] = pg[4 * c + 0];
      pu.u[1] = pg[4 * c + 1];
      pu.u[2] = pg[4 * c + 2];
      pu.u[3] = pg[4 * c + 3];
      o0 = __builtin_amdgcn_mfma_f32_32x32x16_bf16(pu.v, vf[c], o0, 0, 0, 0);
      o1 = __builtin_amdgcn_mfma_f32_32x32x16_bf16(pu.v, vf[2 + c], o1, 0, 0, 0);
    }

    // vf is dead -> rotate in next tile's V (latency covered by next QK+sigmoid)
    if (i < 15) {
#pragma unroll
      for (int c = 0; c < 4; c++)
        vf[c] = *(const s16x8*)&vfp[foff + c * 512];
      foff += 2048;
    }
  }

  // staged 4-way kh reduction in 2 slots: kh{2,3} store -> kh{0,1} add -> pairwise sum
  if (kh >= 2) {
    const int slot = kh - 2;
#pragma unroll
    for (int dh = 0; dh < 2; dh++) {
      f32x16 ov = dh ? o1 : o0;
#pragma unroll
      for (int r = 0; r < 16; r++) {
        int ql = (r & 3) + 8 * (r >> 2) + 4 * hi;
        red[slot * 4096 + (qh * 32 + ql) * 64 + dh * 32 + ln] = ov[r];
      }
    }
  }
  __syncthreads();
  if (kh < 2) {
#pragma unroll
    for (int dh = 0; dh < 2; dh++) {
      f32x16 ov = dh ? o1 : o0;
#pragma unroll
      for (int r = 0; r < 16; r++) {
        int ql = (r & 3) + 8 * (r >> 2) + 4 * hi;
        red[kh * 4096 + (qh * 32 + ql) * 64 + dh * 32 + ln] += ov[r];
      }
    }
  }
  __syncthreads();
  const float4* r0 = (const float4*)red;
  const float4* r1 = (const float4*)(red + 4096);
#pragma unroll
  for (int j = 0; j < 2; j++) {
    int g = t + j * 512;   // 1024 float4s total (64q x 64d)
    float4 s0 = r0[g], s1 = r1[g];
    float4 s;
    s.x = s0.x + s1.x; s.y = s0.y + s1.y; s.z = s0.z + s1.z; s.w = s0.w + s1.w;
    int q = g >> 4, dbase = (g & 15) * 4;
    *(float4*)&out[((size_t)(b * SS + q0 + q)) * DD + h * HDIM + dbase] = s;
  }
}

extern "C" void kernel_launch(void* const* d_in, const int* in_sizes, int n_in,
                              void* d_out, int out_size, void* d_ws, size_t ws_size,
                              hipStream_t stream) {
  const float* x  = (const float*)d_in[0];
  const float* wq = (const float*)d_in[1];
  const float* bq = (const float*)d_in[2];
  const float* wk = (const float*)d_in[3];
  const float* bk = (const float*)d_in[4];
  const float* wv = (const float*)d_in[5];
  const float* bv = (const float*)d_in[6];
  float* out = (float*)d_out;

  constexpr size_t XN = (size_t)BB * SS * DD;

  unsigned short* qo = (unsigned short*)d_ws;
  unsigned short* ko = qo + XN;
  unsigned short* vt = ko + XN;  // 12 MB total ws use

  proj_kernel<<<dim3(64, 8, 3), 256, 0, stream>>>(x, wq, wk, wv, bq, bk, bv, qo, ko, vt);
  attn_kernel<<<dim3(SS / 64, BB * HH), 512, 0, stream>>>(qo, ko, vt, out);
}

// Round 12
// 113.524 us; speedup vs baseline: 2.5971x; 1.0089x over previous
//
#include <hip/hip_runtime.h>
#include <cstdint>
#include <cstddef>

// Problem constants
#define BB   2
#define SS   2048
#define DD   512
#define HH   8
#define HDIM 64
#define XN   ((size_t)BB * SS * DD)   // 2,097,152
#define WN   ((size_t)DD * DD)        //   262,144

typedef __attribute__((ext_vector_type(8)))  short          s16x8;
typedef __attribute__((ext_vector_type(8)))  unsigned short u16x8;
typedef __attribute__((ext_vector_type(16))) float          f32x16;

static __device__ __forceinline__ unsigned short f2bf(float f) {
  union { float f; unsigned u; } x; x.f = f;
  unsigned r = x.u + 0x7fffu + ((x.u >> 16) & 1u);  // RNE
  return (unsigned short)(r >> 16);
}
// truncating bf16 pack: result = bf(hi)<<16 | bf(lo), ONE v_perm_b32
static __device__ __forceinline__ unsigned packtrunc(float lo, float hi) {
  return __builtin_amdgcn_perm(__float_as_uint(hi), __float_as_uint(lo), 0x07060302u);
}

// sigmoid scale folded into Q: -1/sqrt(64) * log2(e)
#define QSCALE (-0.18033688011111543f)

// ---------------- fp32 -> bf16 conversion of x, wq, wk, wv --------------------------
// grid (2048, 4): y=0 -> x (2048 blocks); y=1..3 -> wq/wk/wv (first 256 blocks each).
__global__ __launch_bounds__(256) void cvt_kernel(
    const float* __restrict__ x,
    const float* __restrict__ wq, const float* __restrict__ wk, const float* __restrict__ wv,
    unsigned short* __restrict__ xb, unsigned short* __restrict__ wb3) {
  const int y = blockIdx.y;
  const float* src; unsigned short* dst;
  if (y == 0) { src = x; dst = xb; }
  else {
    if (blockIdx.x >= 256) return;
    src = (y == 1) ? wq : (y == 2) ? wk : wv;
    dst = wb3 + (size_t)(y - 1) * WN;
  }
  int i = (blockIdx.x * 256 + threadIdx.x) * 4;
  float4 f = *(const float4*)(src + i);
  ushort4 o;
  o.x = f2bf(f.x); o.y = f2bf(f.y); o.z = f2bf(f.z); o.w = f2bf(f.w);
  *(ushort4*)(dst + i) = o;
}

// ---------------- QKV projection (bf16 inputs) --------------------------------------
// grid (M/128=32, N/64=8, 3) = 768 blocks = 3/CU. 256 threads = 4 waves; wave owns a
// 32-row strip x 64 cols (2 accs). BK=32, 16 iters, LDS dbuf + reg prefetch, one
// barrier/iter. bf16 staging: no conversion VALU in the loop, half the L2 bytes of
// the fp32 version. Outputs as before:
//   z=0 Q: [B][H][S][HD] pre-scaled by QSCALE
//   z=1 K: MFMA A-frag order (physical key order)
//   z=2 V: MFMA B-frag order with PI key permutation baked in
__global__ __launch_bounds__(256) void proj_kernel(
    const unsigned short* __restrict__ xb, const unsigned short* __restrict__ wb3,
    const float* __restrict__ bq, const float* __restrict__ bk, const float* __restrict__ bv,
    unsigned short* __restrict__ qo, unsigned short* __restrict__ ko,
    unsigned short* __restrict__ vt) {
  __shared__ unsigned short As[2][128 * 40];  // 128 x 32 bf16, pad->40 (proven 0-conflict)
  __shared__ unsigned short Bs[2][64 * 40];

  const int z = blockIdx.z;
  const unsigned short* w = wb3 + (size_t)z * WN;
  const float* bias = (z == 0) ? bq : (z == 1) ? bk : bv;

  const int t = threadIdx.x;
  const int lane = t & 63, wave = t >> 6;
  const int ln = lane & 31, hi = lane >> 5;
  const int m0 = blockIdx.x * 128, n0 = blockIdx.y * 64;

  // staging: A = 512 16B-chunks (2/thread), B = 256 (1/thread); chunk: row=c>>2, off=(c&3)*8
  u16x8 ar[2], br;
#pragma unroll
  for (int i = 0; i < 2; i++) {
    int c = t + i * 256;
    ar[i] = *(const u16x8*)&xb[(size_t)(m0 + (c >> 2)) * DD + (c & 3) * 8];
  }
  br = *(const u16x8*)&w[(size_t)(n0 + (t >> 2)) * DD + (t & 3) * 8];
#pragma unroll
  for (int i = 0; i < 2; i++) {
    int c = t + i * 256;
    *(u16x8*)&As[0][(c >> 2) * 40 + (c & 3) * 8] = ar[i];
  }
  *(u16x8*)&Bs[0][(t >> 2) * 40 + (t & 3) * 8] = br;
  __syncthreads();

  f32x16 acc0 = {}, acc1 = {};

#pragma unroll 2
  for (int kt = 0; kt < 16; kt++) {
    const int cur = kt & 1, nxt = cur ^ 1;
    if (kt < 15) {
      int k0 = (kt + 1) * 32;
#pragma unroll
      for (int i = 0; i < 2; i++) {
        int c = t + i * 256;
        ar[i] = *(const u16x8*)&xb[(size_t)(m0 + (c >> 2)) * DD + k0 + (c & 3) * 8];
      }
      br = *(const u16x8*)&w[(size_t)(n0 + (t >> 2)) * DD + k0 + (t & 3) * 8];
    }
#pragma unroll
    for (int cc = 0; cc < 2; cc++) {
      s16x8 af = *(const s16x8*)&As[cur][(wave * 32 + ln) * 40 + cc * 16 + hi * 8];
      s16x8 b0 = *(const s16x8*)&Bs[cur][(ln) * 40 + cc * 16 + hi * 8];
      s16x8 b1 = *(const s16x8*)&Bs[cur][(32 + ln) * 40 + cc * 16 + hi * 8];
      acc0 = __builtin_amdgcn_mfma_f32_32x32x16_bf16(af, b0, acc0, 0, 0, 0);
      acc1 = __builtin_amdgcn_mfma_f32_32x32x16_bf16(af, b1, acc1, 0, 0, 0);
    }
    if (kt < 15) {
#pragma unroll
      for (int i = 0; i < 2; i++) {
        int c = t + i * 256;
        *(u16x8*)&As[nxt][(c >> 2) * 40 + (c & 3) * 8] = ar[i];
      }
      *(u16x8*)&Bs[nxt][(t >> 2) * 40 + (t & 3) * 8] = br;
    }
    __syncthreads();
  }

  // Epilogue. C layout: col(n) = ln, row(m) local = (r&3) + 8*(r>>2) + 4*hi.
  const int h = blockIdx.y;
  const int bidx = m0 >> 11;
  const int sbase = (m0 & 2047) + wave * 32;   // multiple of 32
  const size_t bhb = (size_t)(bidx * HH + h) * SS * HDIM;
  const int kts = sbase >> 5;

#pragma unroll
  for (int nh = 0; nh < 2; nh++) {
    f32x16 acc = nh ? acc1 : acc0;
    const int hd = nh * 32 + ln;
    const float bval = bias[n0 + hd];

    if (z == 0) {  // Q: [bh][s][hd], scaled
#pragma unroll
      for (int r = 0; r < 16; r++) {
        int s = sbase + (r & 3) + 8 * (r >> 2) + 4 * hi;
        qo[bhb + (size_t)s * HDIM + hd] = f2bf((acc[r] + bval) * QSCALE);
      }
    } else if (z == 1) {  // K fragment order (physical keys)
      const int c = hd >> 4, hk = (hd >> 3) & 1, j = hd & 7;
      unsigned short* kd = ko + bhb + ((size_t)kts * 4 + c) * 512 + j;
#pragma unroll
      for (int r = 0; r < 16; r++) {
        int off = (r & 3) + 8 * (r >> 2) + 4 * hi;  // s & 31
        kd[(hk * 32 + off) * 8] = f2bf(acc[r] + bval);
      }
    } else {  // V fragment order WITH pi permutation: physical key kappa=8g+4hi+j
      unsigned short* vd = vt + bhb + ((size_t)kts * 4 + nh * 2) * 512 + hi * 256 + ln * 8;
#pragma unroll
      for (int g = 0; g < 4; g++) {
        unsigned short* vg = vd + (g >> 1) * 512 + (g & 1) * 4;
#pragma unroll
        for (int j = 0; j < 4; j += 2) {
          unsigned pk = (unsigned)f2bf(acc[g * 4 + j] + bval) |
                        ((unsigned)f2bf(acc[g * 4 + j + 1] + bval) << 16);
          *(unsigned*)&vg[j] = pk;
        }
      }
    }
  }
}

// ---------------- fused sigmoid attention: 8-wave 64q blocks, rotated frags ---------
// (unchanged from R11 — control) grid (32,16) x 512 thr = 8 waves = (qh,kh) 2x4.
// K/V frag-direct contiguous 1KB loads, single-buffered rotation, pi-permuted V,
// zero loop barriers. launch_bounds (512,4): 4 waves/SIMD, body fits 128 regs.
__global__ __launch_bounds__(512, 4) void attn_kernel(
    const unsigned short* __restrict__ qb,
    const unsigned short* __restrict__ kfb,
    const unsigned short* __restrict__ vfb,
    float* __restrict__ out) {
  __shared__ __align__(16) float red[2 * 4096];  // 32 KB, 2 reduction slots

  const int t = threadIdx.x;
  const int lane = t & 63, wave = t >> 6;   // wave 0..7
  const int ln = lane & 31, hi = lane >> 5;
  const int qh = wave & 1, kh = wave >> 1;  // qh: 32q half, kh: key quarter
  const int fid = blockIdx.y * 32 + blockIdx.x;
  const int bh = fid & 15, qx = fid >> 4;
  const int b = bh >> 3, h = bh & 7;
  const unsigned short* qp = qb + (size_t)bh * SS * HDIM;
  const unsigned short* kfp = kfb + (size_t)bh * SS * HDIM;
  const unsigned short* vfp = vfb + (size_t)bh * SS * HDIM;
  const int q0 = qx * 64;

  s16x8 qf[4];
#pragma unroll
  for (int c = 0; c < 4; c++)
    qf[c] = *(const s16x8*)&qp[(size_t)(q0 + qh * 32 + ln) * HDIM + c * 16 + hi * 8];

  f32x16 o0 = {}, o1 = {};

  s16x8 kf[4], vf[4];
  int foff = kh * 16 * 2048 + lane * 8;
#pragma unroll
  for (int c = 0; c < 4; c++) {
    kf[c] = *(const s16x8*)&kfp[foff + c * 512];
    vf[c] = *(const s16x8*)&vfp[foff + c * 512];
  }
  foff += 2048;

#pragma unroll 1
  for (int i = 0; i < 16; i++) {
    f32x16 st = {};
#pragma unroll
    for (int c = 0; c < 4; c++)
      st = __builtin_amdgcn_mfma_f32_32x32x16_bf16(kf[c], qf[c], st, 0, 0, 0);

    if (i < 15) {
#pragma unroll
      for (int c = 0; c < 4; c++)
        kf[c] = *(const s16x8*)&kfp[foff + c * 512];
    }

    unsigned pg[8];
#pragma unroll
    for (int g = 0; g < 4; g++) {
      float p0 = __builtin_amdgcn_rcpf(1.0f + __builtin_amdgcn_exp2f(st[4 * g + 0]));
      float p1 = __builtin_amdgcn_rcpf(1.0f + __builtin_amdgcn_exp2f(st[4 * g + 1]));
      float p2 = __builtin_amdgcn_rcpf(1.0f + __builtin_amdgcn_exp2f(st[4 * g + 2]));
      float p3 = __builtin_amdgcn_rcpf(1.0f + __builtin_amdgcn_exp2f(st[4 * g + 3]));
      pg[2 * g]     = packtrunc(p0, p1);
      pg[2 * g + 1] = packtrunc(p2, p3);
    }

#pragma unroll
    for (int c = 0; c < 2; c++) {
      union { unsigned u[4]; s16x8 v; } pu;
      pu.u[0] = pg[4 * c + 0];
      pu.u[1] = pg[4 * c + 1];
      pu.u[2] = pg[4 * c + 2];
      pu.u[3] = pg[4 * c + 3];
      o0 = __builtin_amdgcn_mfma_f32_32x32x16_bf16(pu.v, vf[c], o0, 0, 0, 0);
      o1 = __builtin_amdgcn_mfma_f32_32x32x16_bf16(pu.v, vf[2 + c], o1, 0, 0, 0);
    }

    if (i < 15) {
#pragma unroll
      for (int c = 0; c < 4; c++)
        vf[c] = *(const s16x8*)&vfp[foff + c * 512];
      foff += 2048;
    }
  }

  if (kh >= 2) {
    const int slot = kh - 2;
#pragma unroll
    for (int dh = 0; dh < 2; dh++) {
      f32x16 ov = dh ? o1 : o0;
#pragma unroll
      for (int r = 0; r < 16; r++) {
        int ql = (r & 3) + 8 * (r >> 2) + 4 * hi;
        red[slot * 4096 + (qh * 32 + ql) * 64 + dh * 32 + ln] = ov[r];
      }
    }
  }
  __syncthreads();
  if (kh < 2) {
#pragma unroll
    for (int dh = 0; dh < 2; dh++) {
      f32x16 ov = dh ? o1 : o0;
#pragma unroll
      for (int r = 0; r < 16; r++) {
        int ql = (r & 3) + 8 * (r >> 2) + 4 * hi;
        red[kh * 4096 + (qh * 32 + ql) * 64 + dh * 32 + ln] += ov[r];
      }
    }
  }
  __syncthreads();
  const float4* r0 = (const float4*)red;
  const float4* r1 = (const float4*)(red + 4096);
#pragma unroll
  for (int j = 0; j < 2; j++) {
    int g = t + j * 512;
    float4 s0 = r0[g], s1 = r1[g];
    float4 s;
    s.x = s0.x + s1.x; s.y = s0.y + s1.y; s.z = s0.z + s1.z; s.w = s0.w + s1.w;
    int q = g >> 4, dbase = (g & 15) * 4;
    *(float4*)&out[((size_t)(b * SS + q0 + q)) * DD + h * HDIM + dbase] = s;
  }
}

extern "C" void kernel_launch(void* const* d_in, const int* in_sizes, int n_in,
                              void* d_out, int out_size, void* d_ws, size_t ws_size,
                              hipStream_t stream) {
  const float* x  = (const float*)d_in[0];
  const float* wq = (const float*)d_in[1];
  const float* bq = (const float*)d_in[2];
  const float* wk = (const float*)d_in[3];
  const float* bk = (const float*)d_in[4];
  const float* wv = (const float*)d_in[5];
  const float* bv = (const float*)d_in[6];
  float* out = (float*)d_out;

  unsigned short* xb = (unsigned short*)d_ws;
  unsigned short* wb = xb + XN;          // 3 weight matrices contiguous
  unsigned short* qo = wb + 3 * WN;
  unsigned short* ko = qo + XN;
  unsigned short* vt = ko + XN;          // ~18.5 MB total ws use

  cvt_kernel<<<dim3(2048, 4), 256, 0, stream>>>(x, wq, wk, wv, xb, wb);
  proj_kernel<<<dim3(32, 8, 3), 256, 0, stream>>>(xb, wb, bq, bk, bv, qo, ko, vt);
  attn_kernel<<<dim3(SS / 64, BB * HH), 512, 0, stream>>>(qo, ko, vt, out);
}

// Round 13
// 112.577 us; speedup vs baseline: 2.6190x; 1.0084x over previous
//
#include <hip/hip_runtime.h>
#include <cstdint>
#include <cstddef>

// Problem constants
#define BB   2
#define SS   2048
#define DD   512
#define HH   8
#define HDIM 64
#define XN   ((size_t)BB * SS * DD)   // 2,097,152
#define WN   ((size_t)DD * DD)        //   262,144

typedef __attribute__((ext_vector_type(8)))  short          s16x8;
typedef __attribute__((ext_vector_type(8)))  unsigned short u16x8;
typedef __attribute__((ext_vector_type(16))) float          f32x16;

static __device__ __forceinline__ unsigned short f2bf(float f) {
  union { float f; unsigned u; } x; x.f = f;
  unsigned r = x.u + 0x7fffu + ((x.u >> 16) & 1u);  // RNE
  return (unsigned short)(r >> 16);
}
// truncating bf16 pack: result = bf(hi)<<16 | bf(lo), ONE v_perm_b32
static __device__ __forceinline__ unsigned packtrunc(float lo, float hi) {
  return __builtin_amdgcn_perm(__float_as_uint(hi), __float_as_uint(lo), 0x07060302u);
}

// sigmoid scale folded into Q: -1/sqrt(64) * log2(e)
#define QSCALE (-0.18033688011111543f)

// ---------------- fp32 -> bf16 conversion of x, wq, wk, wv --------------------------
// grid (2048, 4): y=0 -> x (2048 blocks); y=1..3 -> wq/wk/wv (first 256 blocks each).
__global__ __launch_bounds__(256) void cvt_kernel(
    const float* __restrict__ x,
    const float* __restrict__ wq, const float* __restrict__ wk, const float* __restrict__ wv,
    unsigned short* __restrict__ xb, unsigned short* __restrict__ wb3) {
  const int y = blockIdx.y;
  const float* src; unsigned short* dst;
  if (y == 0) { src = x; dst = xb; }
  else {
    if (blockIdx.x >= 256) return;
    src = (y == 1) ? wq : (y == 2) ? wk : wv;
    dst = wb3 + (size_t)(y - 1) * WN;
  }
  int i = (blockIdx.x * 256 + threadIdx.x) * 4;
  float4 f = *(const float4*)(src + i);
  ushort4 o;
  o.x = f2bf(f.x); o.y = f2bf(f.y); o.z = f2bf(f.z); o.w = f2bf(f.w);
  *(ushort4*)(dst + i) = o;
}

// ---------------- QKV projection (bf16 inputs) --------------------------------------
// grid (M/128=32, N/64=8, 3) = 768 blocks = 3/CU. 256 threads = 4 waves; wave owns a
// 32-row strip x 64 cols (2 accs). BK=32, 16 iters, LDS dbuf + reg prefetch.
// Outputs: z=0 Q [B][H][S][HD] scaled; z=1 K MFMA A-frag order; z=2 V B-frag order
// with PI key permutation baked in.
__global__ __launch_bounds__(256) void proj_kernel(
    const unsigned short* __restrict__ xb, const unsigned short* __restrict__ wb3,
    const float* __restrict__ bq, const float* __restrict__ bk, const float* __restrict__ bv,
    unsigned short* __restrict__ qo, unsigned short* __restrict__ ko,
    unsigned short* __restrict__ vt) {
  __shared__ unsigned short As[2][128 * 40];
  __shared__ unsigned short Bs[2][64 * 40];

  const int z = blockIdx.z;
  const unsigned short* w = wb3 + (size_t)z * WN;
  const float* bias = (z == 0) ? bq : (z == 1) ? bk : bv;

  const int t = threadIdx.x;
  const int lane = t & 63, wave = t >> 6;
  const int ln = lane & 31, hi = lane >> 5;
  const int m0 = blockIdx.x * 128, n0 = blockIdx.y * 64;

  u16x8 ar[2], br;
#pragma unroll
  for (int i = 0; i < 2; i++) {
    int c = t + i * 256;
    ar[i] = *(const u16x8*)&xb[(size_t)(m0 + (c >> 2)) * DD + (c & 3) * 8];
  }
  br = *(const u16x8*)&w[(size_t)(n0 + (t >> 2)) * DD + (t & 3) * 8];
#pragma unroll
  for (int i = 0; i < 2; i++) {
    int c = t + i * 256;
    *(u16x8*)&As[0][(c >> 2) * 40 + (c & 3) * 8] = ar[i];
  }
  *(u16x8*)&Bs[0][(t >> 2) * 40 + (t & 3) * 8] = br;
  __syncthreads();

  f32x16 acc0 = {}, acc1 = {};

#pragma unroll 2
  for (int kt = 0; kt < 16; kt++) {
    const int cur = kt & 1, nxt = cur ^ 1;
    if (kt < 15) {
      int k0 = (kt + 1) * 32;
#pragma unroll
      for (int i = 0; i < 2; i++) {
        int c = t + i * 256;
        ar[i] = *(const u16x8*)&xb[(size_t)(m0 + (c >> 2)) * DD + k0 + (c & 3) * 8];
      }
      br = *(const u16x8*)&w[(size_t)(n0 + (t >> 2)) * DD + k0 + (t & 3) * 8];
    }
#pragma unroll
    for (int cc = 0; cc < 2; cc++) {
      s16x8 af = *(const s16x8*)&As[cur][(wave * 32 + ln) * 40 + cc * 16 + hi * 8];
      s16x8 b0 = *(const s16x8*)&Bs[cur][(ln) * 40 + cc * 16 + hi * 8];
      s16x8 b1 = *(const s16x8*)&Bs[cur][(32 + ln) * 40 + cc * 16 + hi * 8];
      acc0 = __builtin_amdgcn_mfma_f32_32x32x16_bf16(af, b0, acc0, 0, 0, 0);
      acc1 = __builtin_amdgcn_mfma_f32_32x32x16_bf16(af, b1, acc1, 0, 0, 0);
    }
    if (kt < 15) {
#pragma unroll
      for (int i = 0; i < 2; i++) {
        int c = t + i * 256;
        *(u16x8*)&As[nxt][(c >> 2) * 40 + (c & 3) * 8] = ar[i];
      }
      *(u16x8*)&Bs[nxt][(t >> 2) * 40 + (t & 3) * 8] = br;
    }
    __syncthreads();
  }

  const int h = blockIdx.y;
  const int bidx = m0 >> 11;
  const int sbase = (m0 & 2047) + wave * 32;
  const size_t bhb = (size_t)(bidx * HH + h) * SS * HDIM;
  const int kts = sbase >> 5;

#pragma unroll
  for (int nh = 0; nh < 2; nh++) {
    f32x16 acc = nh ? acc1 : acc0;
    const int hd = nh * 32 + ln;
    const float bval = bias[n0 + hd];

    if (z == 0) {
#pragma unroll
      for (int r = 0; r < 16; r++) {
        int s = sbase + (r & 3) + 8 * (r >> 2) + 4 * hi;
        qo[bhb + (size_t)s * HDIM + hd] = f2bf((acc[r] + bval) * QSCALE);
      }
    } else if (z == 1) {
      const int c = hd >> 4, hk = (hd >> 3) & 1, j = hd & 7;
      unsigned short* kd = ko + bhb + ((size_t)kts * 4 + c) * 512 + j;
#pragma unroll
      for (int r = 0; r < 16; r++) {
        int off = (r & 3) + 8 * (r >> 2) + 4 * hi;
        kd[(hk * 32 + off) * 8] = f2bf(acc[r] + bval);
      }
    } else {
      unsigned short* vd = vt + bhb + ((size_t)kts * 4 + nh * 2) * 512 + hi * 256 + ln * 8;
#pragma unroll
      for (int g = 0; g < 4; g++) {
        unsigned short* vg = vd + (g >> 1) * 512 + (g & 1) * 4;
#pragma unroll
        for (int j = 0; j < 4; j += 2) {
          unsigned pk = (unsigned)f2bf(acc[g * 4 + j] + bval) |
                        ((unsigned)f2bf(acc[g * 4 + j + 1] + bval) << 16);
          *(unsigned*)&vg[j] = pk;
        }
      }
    }
  }
}

// ---------------- fused sigmoid attention: 64q per WAVE (traffic halved) ------------
// grid (S/128=16, B*H=16) = 256 blocks x 512 thr = 8 waves = (qp,kh) 2x4: each wave
// holds TWO 32-q sets (qp half = 64 queries) x key quarter (16 tiles of 32). Each K/V
// tile load now feeds 16 MFMAs (was 8) -> VMEM operand traffic halves (512->256 MB);
// trans/MFMA demand invariant. Lost TLP (2 waves/SIMD at ~165 regs) is compensated by
// doubled intra-wave ILP: QK(qs1) overlaps sigmoid(qs0). Single-buffered rotation,
// pi-permuted V, zero loop barriers. 64 KB staged kh-reduction.
__global__ __launch_bounds__(512, 2) void attn_kernel(
    const unsigned short* __restrict__ qb,
    const unsigned short* __restrict__ kfb,
    const unsigned short* __restrict__ vfb,
    float* __restrict__ out) {
  __shared__ __align__(16) float red[2 * 8192];  // 64 KB, 2 slots of 128q x 64d

  const int t = threadIdx.x;
  const int lane = t & 63, wave = t >> 6;   // wave 0..7
  const int ln = lane & 31, hi = lane >> 5;
  const int qp = wave & 1, kh = wave >> 1;  // qp: 64-q half, kh: key quarter
  // XCD swizzle: blocks of one bh at ids ≡ mod 16 -> same XCD
  const int fid = blockIdx.y * 16 + blockIdx.x;
  const int bh = fid & 15, qx = fid >> 4;
  const int b = bh >> 3, h = bh & 7;
  const unsigned short* qp_ = qb + (size_t)bh * SS * HDIM;
  const unsigned short* kfp = kfb + (size_t)bh * SS * HDIM;
  const unsigned short* vfp = vfb + (size_t)bh * SS * HDIM;
  const int q0 = qx * 128 + qp * 64;

  // TWO Q fragment sets (B-operand: n=q on lane, k=d)
  s16x8 qf[2][4];
#pragma unroll
  for (int qs = 0; qs < 2; qs++)
#pragma unroll
    for (int c = 0; c < 4; c++)
      qf[qs][c] = *(const s16x8*)&qp_[(size_t)(q0 + qs * 32 + ln) * HDIM + c * 16 + hi * 8];

  f32x16 o00 = {}, o01 = {}, o10 = {}, o11 = {};

  s16x8 kf[4], vf[4];
  int foff = kh * 16 * 2048 + lane * 8;
#pragma unroll
  for (int c = 0; c < 4; c++) {
    kf[c] = *(const s16x8*)&kfp[foff + c * 512];
    vf[c] = *(const s16x8*)&vfp[foff + c * 512];
  }
  foff += 2048;

#pragma unroll 1
  for (int i = 0; i < 16; i++) {
    // QK^T for both q-sets (independent chains — ILP)
    f32x16 st0 = {}, st1 = {};
#pragma unroll
    for (int c = 0; c < 4; c++) {
      st0 = __builtin_amdgcn_mfma_f32_32x32x16_bf16(kf[c], qf[0][c], st0, 0, 0, 0);
      st1 = __builtin_amdgcn_mfma_f32_32x32x16_bf16(kf[c], qf[1][c], st1, 0, 0, 0);
    }

    // kf dead -> rotate next tile's K (covered by sigmoid+PV)
    if (i < 15) {
#pragma unroll
      for (int c = 0; c < 4; c++)
        kf[c] = *(const s16x8*)&kfp[foff + c * 512];
    }

    // sigmoid both sets; pi layout -> pg[qs][4c..4c+3] is the PV A-operand verbatim
    unsigned pg[2][8];
#pragma unroll
    for (int qs = 0; qs < 2; qs++) {
      f32x16 st = qs ? st1 : st0;
#pragma unroll
      for (int g = 0; g < 4; g++) {
        float p0 = __builtin_amdgcn_rcpf(1.0f + __builtin_amdgcn_exp2f(st[4 * g + 0]));
        float p1 = __builtin_amdgcn_rcpf(1.0f + __builtin_amdgcn_exp2f(st[4 * g + 1]));
        float p2 = __builtin_amdgcn_rcpf(1.0f + __builtin_amdgcn_exp2f(st[4 * g + 2]));
        float p3 = __builtin_amdgcn_rcpf(1.0f + __builtin_amdgcn_exp2f(st[4 * g + 3]));
        pg[qs][2 * g]     = packtrunc(p0, p1);
        pg[qs][2 * g + 1] = packtrunc(p2, p3);
      }
    }

    // PV: 8 MFMAs reusing the same vf for both q-sets
#pragma unroll
    for (int c = 0; c < 2; c++) {
#pragma unroll
      for (int qs = 0; qs < 2; qs++) {
        union { unsigned u[4]; s16x8 v; } pu;
        pu.u[0] = pg[qs][4 * c + 0];
        pu.u[1] = pg[qs][4 * c + 1];
        pu.u[2] = pg[qs][4 * c + 2];
        pu.u[3] = pg[qs][4 * c + 3];
        if (qs == 0) {
          o00 = __builtin_amdgcn_mfma_f32_32x32x16_bf16(pu.v, vf[c], o00, 0, 0, 0);
          o01 = __builtin_amdgcn_mfma_f32_32x32x16_bf16(pu.v, vf[2 + c], o01, 0, 0, 0);
        } else {
          o10 = __builtin_amdgcn_mfma_f32_32x32x16_bf16(pu.v, vf[c], o10, 0, 0, 0);
          o11 = __builtin_amdgcn_mfma_f32_32x32x16_bf16(pu.v, vf[2 + c], o11, 0, 0, 0);
        }
      }
    }

    // vf dead -> rotate next tile's V (covered by next QK+sigmoid)
    if (i < 15) {
#pragma unroll
      for (int c = 0; c < 4; c++)
        vf[c] = *(const s16x8*)&vfp[foff + c * 512];
      foff += 2048;
    }
  }

  // staged 4-way kh reduction: kh{2,3} -> slots, kh{0,1} add, then pairwise sum.
  // slot index: 128q x 64d, q_local = qp*64 + qs*32 + C-row
  if (kh >= 2) {
    float* slot = red + (kh - 2) * 8192;
#pragma unroll
    for (int qs = 0; qs < 2; qs++)
#pragma unroll
      for (int dh = 0; dh < 2; dh++) {
        f32x16 ov = qs ? (dh ? o11 : o10) : (dh ? o01 : o00);
#pragma unroll
        for (int r = 0; r < 16; r++) {
          int ql = qp * 64 + qs * 32 + (r & 3) + 8 * (r >> 2) + 4 * hi;
          slot[ql * 64 + dh * 32 + ln] = ov[r];
        }
      }
  }
  __syncthreads();
  if (kh < 2) {
    float* slot = red + kh * 8192;
#pragma unroll
    for (int qs = 0; qs < 2; qs++)
#pragma unroll
      for (int dh = 0; dh < 2; dh++) {
        f32x16 ov = qs ? (dh ? o11 : o10) : (dh ? o01 : o00);
#pragma unroll
        for (int r = 0; r < 16; r++) {
          int ql = qp * 64 + qs * 32 + (r & 3) + 8 * (r >> 2) + 4 * hi;
          slot[ql * 64 + dh * 32 + ln] += ov[r];
        }
      }
  }
  __syncthreads();
  const float4* r0 = (const float4*)red;
  const float4* r1 = (const float4*)(red + 8192);
  const int qblk = qx * 128;
#pragma unroll
  for (int j = 0; j < 4; j++) {
    int g = t + j * 512;   // 2048 float4s total (128q x 64d)
    float4 s0 = r0[g], s1 = r1[g];
    float4 s;
    s.x = s0.x + s1.x; s.y = s0.y + s1.y; s.z = s0.z + s1.z; s.w = s0.w + s1.w;
    int q = g >> 4, dbase = (g & 15) * 4;
    *(float4*)&out[((size_t)(b * SS + qblk + q)) * DD + h * HDIM + dbase] = s;
  }
}

extern "C" void kernel_launch(void* const* d_in, const int* in_sizes, int n_in,
                              void* d_out, int out_size, void* d_ws, size_t ws_size,
                              hipStream_t stream) {
  const float* x  = (const float*)d_in[0];
  const float* wq = (const float*)d_in[1];
  const float* bq = (const float*)d_in[2];
  const float* wk = (const float*)d_in[3];
  const float* bk = (const float*)d_in[4];
  const float* wv = (const float*)d_in[5];
  const float* bv = (const float*)d_in[6];
  float* out = (float*)d_out;

  unsigned short* xb = (unsigned short*)d_ws;
  unsigned short* wb = xb + XN;
  unsigned short* qo = wb + 3 * WN;
  unsigned short* ko = qo + XN;
  unsigned short* vt = ko + XN;   // ~18.5 MB total ws use

  cvt_kernel<<<dim3(2048, 4), 256, 0, stream>>>(x, wq, wk, wv, xb, wb);
  proj_kernel<<<dim3(32, 8, 3), 256, 0, stream>>>(xb, wb, bq, bk, bv, qo, ko, vt);
  attn_kernel<<<dim3(SS / 128, BB * HH), 512, 0, stream>>>(qo, ko, vt, out);
}